// Round 1
// baseline (1681.183 us; speedup 1.0000x reference)
//
#include <hip/hip_runtime.h>
#include <math.h>

#define B_ 2
#define L_ 2048
#define D_ 512
#define H_ 16
#define HD_ 32
#define FF_ 2048
#define BL_ 4096
#define EPS_ 1e-5f

constexpr int TM = 128;
constexpr int TN = 64;
constexpr int BK = 16;

// ---------------------------------------------------------------- wave reduce
__device__ __forceinline__ float wsum(float v) {
#pragma unroll
  for (int o = 32; o; o >>= 1) v += __shfl_xor(v, o);
  return v;
}

// ---------------------------------------------------------------- GEMM NT: C = A(M,K) @ W(N,K)^T + bias[col] (+res) (+gelu)
template <int ACT, int RES>
__global__ __launch_bounds__(256) void gemm_nt_k(
    const float* __restrict__ A, const float* __restrict__ W,
    const float* __restrict__ bias, const float* __restrict__ res,
    float* __restrict__ C, int M, int N, int Kd) {
  __shared__ float Ask[BK][TM + 4];
  __shared__ float Wsk[BK][TN + 4];
  const int tid = threadIdx.x;
  const int tx = tid & 15;
  const int ty = tid >> 4;
  const int bm = blockIdx.y * TM;
  const int bn = blockIdx.x * TN;
  float acc[8][4] = {};
  for (int k0 = 0; k0 < Kd; k0 += BK) {
    {
      int r = tid >> 1, c = (tid & 1) * 8;
      const float* ap = A + (size_t)(bm + r) * Kd + k0 + c;
      float4 a0 = *(const float4*)ap;
      float4 a1 = *(const float4*)(ap + 4);
      Ask[c + 0][r] = a0.x; Ask[c + 1][r] = a0.y; Ask[c + 2][r] = a0.z; Ask[c + 3][r] = a0.w;
      Ask[c + 4][r] = a1.x; Ask[c + 5][r] = a1.y; Ask[c + 6][r] = a1.z; Ask[c + 7][r] = a1.w;
    }
    {
      int r = tid >> 2, c = (tid & 3) * 4;
      const float* wp = W + (size_t)(bn + r) * Kd + k0 + c;
      float4 w0 = *(const float4*)wp;
      Wsk[c + 0][r] = w0.x; Wsk[c + 1][r] = w0.y; Wsk[c + 2][r] = w0.z; Wsk[c + 3][r] = w0.w;
    }
    __syncthreads();
#pragma unroll
    for (int kk = 0; kk < BK; ++kk) {
      float4 a0 = *(const float4*)&Ask[kk][ty * 4];
      float4 a1 = *(const float4*)&Ask[kk][64 + ty * 4];
      float4 w0 = *(const float4*)&Wsk[kk][tx * 4];
      float av[8] = {a0.x, a0.y, a0.z, a0.w, a1.x, a1.y, a1.z, a1.w};
      float wv[4] = {w0.x, w0.y, w0.z, w0.w};
#pragma unroll
      for (int i = 0; i < 8; ++i)
#pragma unroll
        for (int j = 0; j < 4; ++j) acc[i][j] += av[i] * wv[j];
    }
    __syncthreads();
  }
#pragma unroll
  for (int i = 0; i < 8; ++i) {
    int m = bm + ((i < 4) ? (ty * 4 + i) : (64 + ty * 4 + i - 4));
    int n = bn + tx * 4;
    float4 o;
    float* po = &o.x;
#pragma unroll
    for (int j = 0; j < 4; ++j) {
      float v = acc[i][j] + bias[n + j];
      if (RES) v += res[(size_t)m * N + n + j];
      if (ACT == 1) v = 0.5f * v * (1.0f + erff(v * 0.70710678118654752f));
      po[j] = v;
    }
    *(float4*)&C[(size_t)m * N + n] = o;
  }
}

// ---------------------------------------------------------------- GEMM NN: C = A(M,K) @ Bm(K,N) + bias[row], batched over z
__global__ __launch_bounds__(256) void gemm_nn_k(
    const float* __restrict__ A, const float* __restrict__ Bm,
    const float* __restrict__ biasRow, float* __restrict__ C,
    int M, int N, int Kd, long strideB, long strideC) {
  __shared__ float Ask[BK][TM + 4];
  __shared__ float Bsk[BK][TN + 4];
  const float* Bp = Bm + (size_t)blockIdx.z * strideB;
  float* Cp = C + (size_t)blockIdx.z * strideC;
  const int tid = threadIdx.x;
  const int tx = tid & 15;
  const int ty = tid >> 4;
  const int bm = blockIdx.y * TM;
  const int bn = blockIdx.x * TN;
  float acc[8][4] = {};
  for (int k0 = 0; k0 < Kd; k0 += BK) {
    {
      int r = tid >> 1, c = (tid & 1) * 8;
      const float* ap = A + (size_t)(bm + r) * Kd + k0 + c;
      float4 a0 = *(const float4*)ap;
      float4 a1 = *(const float4*)(ap + 4);
      Ask[c + 0][r] = a0.x; Ask[c + 1][r] = a0.y; Ask[c + 2][r] = a0.z; Ask[c + 3][r] = a0.w;
      Ask[c + 4][r] = a1.x; Ask[c + 5][r] = a1.y; Ask[c + 6][r] = a1.z; Ask[c + 7][r] = a1.w;
    }
    {
      int kr = tid >> 4, cc = (tid & 15) * 4;
      float4 b0 = *(const float4*)&Bp[(size_t)(k0 + kr) * N + bn + cc];
      *(float4*)&Bsk[kr][cc] = b0;
    }
    __syncthreads();
#pragma unroll
    for (int kk = 0; kk < BK; ++kk) {
      float4 a0 = *(const float4*)&Ask[kk][ty * 4];
      float4 a1 = *(const float4*)&Ask[kk][64 + ty * 4];
      float4 b0 = *(const float4*)&Bsk[kk][tx * 4];
      float av[8] = {a0.x, a0.y, a0.z, a0.w, a1.x, a1.y, a1.z, a1.w};
      float bv[4] = {b0.x, b0.y, b0.z, b0.w};
#pragma unroll
      for (int i = 0; i < 8; ++i)
#pragma unroll
        for (int j = 0; j < 4; ++j) acc[i][j] += av[i] * bv[j];
    }
    __syncthreads();
  }
#pragma unroll
  for (int i = 0; i < 8; ++i) {
    int m = bm + ((i < 4) ? (ty * 4 + i) : (64 + ty * 4 + i - 4));
    int n = bn + tx * 4;
    float bm_ = biasRow[m];
    float4 o;
    float* po = &o.x;
#pragma unroll
    for (int j = 0; j < 4; ++j) po[j] = acc[i][j] + bm_;
    *(float4*)&Cp[(size_t)m * N + n] = o;
  }
}

// ---------------------------------------------------------------- RoPE table (matches reference's interleaved slicing of [cos|sin])
__global__ void rope_table_k(float* __restrict__ tab) {
  int t = blockIdx.x * 256 + threadIdx.x;  // L*16
  if (t >= L_ * 16) return;
  int i = t & 15, l = t >> 4;
  float cv, sv;
  if (i < 8) {
    float inv0 = 1.0f / powf(10000.0f, (float)(2 * i) / 16.0f);
    float inv1 = 1.0f / powf(10000.0f, (float)(2 * i + 1) / 16.0f);
    cv = cosf((float)l * inv0);
    sv = cosf((float)l * inv1);
  } else {
    int ii = i - 8;
    float inv0 = 1.0f / powf(10000.0f, (float)(2 * ii) / 16.0f);
    float inv1 = 1.0f / powf(10000.0f, (float)(2 * ii + 1) / 16.0f);
    cv = sinf((float)l * inv0);
    sv = sinf((float)l * inv1);
  }
  tab[l * 32 + i] = cv;
  tab[l * 32 + 16 + i] = sv;
}

// ---------------------------------------------------------------- rope + (B,L,D)->(B,H,L,HD)
__global__ __launch_bounds__(256) void rope_k(const float* __restrict__ xin,
                                              const float* __restrict__ tab,
                                              float* __restrict__ out) {
  int t = blockIdx.x * 256 + threadIdx.x;  // B*L*H*16 = 1048576
  int i = t & 15;
  int h = (t >> 4) & 15;
  int l = (t >> 8) & 2047;
  int b = t >> 19;
  const float* xp = xin + ((size_t)(b * L_ + l)) * D_ + h * HD_;
  float xe = xp[2 * i], xo = xp[2 * i + 1];
  float cv = tab[l * 32 + i], sv = tab[l * 32 + 16 + i];
  float* op = out + (((size_t)(b * H_ + h)) * L_ + l) * HD_;
  op[i] = xe * cv - xo * sv;
  op[16 + i] = xe * sv + xo * cv;
}

// ---------------------------------------------------------------- plain (B,L,D)->(B,H,L,HD)
__global__ __launch_bounds__(256) void bhld_k(const float* __restrict__ xin,
                                              float* __restrict__ out) {
  int t = blockIdx.x * 256 + threadIdx.x;  // B*L*D = 2097152
  int d = t & 31;
  int h = (t >> 5) & 15;
  int l = (t >> 9) & 2047;
  int b = t >> 20;
  out[(((size_t)(b * H_ + h)) * L_ + l) * HD_ + d] =
      xin[((size_t)(b * L_ + l)) * D_ + h * HD_ + d];
}

// ---------------------------------------------------------------- flash attention f32 (1 query/thread), ALiBi added, non-causal
__global__ __launch_bounds__(256) void attn_k(const float* __restrict__ q,
                                              const float* __restrict__ k,
                                              const float* __restrict__ v,
                                              float* __restrict__ ctx) {
  __shared__ float Ks[64][HD_];
  __shared__ float Vs[64][HD_];
  int bh = blockIdx.x >> 3;  // L/256 = 8 tiles per (b,h)
  int tile = blockIdx.x & 7;
  int h = bh & 15, b = bh >> 4;
  int lq = tile * 256 + threadIdx.x;
  const float scale = 0.1767766952966369f;  // 32^-0.5
  float qr[HD_];
  const float* qp = q + ((size_t)bh * L_ + lq) * HD_;
#pragma unroll
  for (int d = 0; d < HD_; ++d) qr[d] = qp[d] * scale;
  float slope = exp2f(-0.5f * (float)h);
  float mval = -1e30f, lsum = 0.f;
  float acc[HD_] = {};
  const float* kbase = k + (size_t)bh * L_ * HD_;
  const float* vbase = v + (size_t)bh * L_ * HD_;
  for (int t0 = 0; t0 < L_; t0 += 64) {
    __syncthreads();
    int r = threadIdx.x >> 2, c = (threadIdx.x & 3) * 8;
    *(float4*)&Ks[r][c] = *(const float4*)&kbase[(size_t)(t0 + r) * HD_ + c];
    *(float4*)&Ks[r][c + 4] = *(const float4*)&kbase[(size_t)(t0 + r) * HD_ + c + 4];
    *(float4*)&Vs[r][c] = *(const float4*)&vbase[(size_t)(t0 + r) * HD_ + c];
    *(float4*)&Vs[r][c + 4] = *(const float4*)&vbase[(size_t)(t0 + r) * HD_ + c + 4];
    __syncthreads();
#pragma unroll 1
    for (int j0 = 0; j0 < 64; j0 += 16) {
      float sc[16];
#pragma unroll
      for (int jj = 0; jj < 16; ++jj) {
        const float* kr = &Ks[j0 + jj][0];
        float s0 = 0, s1 = 0, s2 = 0, s3 = 0;
#pragma unroll
        for (int d = 0; d < HD_; d += 4) {
          s0 += qr[d + 0] * kr[d + 0];
          s1 += qr[d + 1] * kr[d + 1];
          s2 += qr[d + 2] * kr[d + 2];
          s3 += qr[d + 3] * kr[d + 3];
        }
        int dist = lq - (t0 + j0 + jj);
        float al = (dist > 0) ? slope * (float)dist : 0.f;
        sc[jj] = (s0 + s1) + (s2 + s3) + al;
      }
      float mt = mval;
#pragma unroll
      for (int jj = 0; jj < 16; ++jj) mt = fmaxf(mt, sc[jj]);
      float corr = __expf(mval - mt);
      mval = mt;
      lsum *= corr;
#pragma unroll
      for (int d = 0; d < HD_; ++d) acc[d] *= corr;
#pragma unroll
      for (int jj = 0; jj < 16; ++jj) {
        float p = __expf(sc[jj] - mt);
        lsum += p;
        const float* vr = &Vs[j0 + jj][0];
#pragma unroll
        for (int d = 0; d < HD_; ++d) acc[d] += p * vr[d];
      }
    }
  }
  float invl = 1.f / lsum;
  float* op = ctx + ((size_t)(b * L_ + lq)) * D_ + h * HD_;
#pragma unroll
  for (int d = 0; d < HD_; d += 4) {
    float4 o = {acc[d] * invl, acc[d + 1] * invl, acc[d + 2] * invl, acc[d + 3] * invl};
    *(float4*)&op[d] = o;
  }
}

// ---------------------------------------------------------------- x0 = res + LN(x; g1,b1), xln = LN(x0; g2,b2)
__global__ __launch_bounds__(64) void ln_res_ln_k(
    const float* __restrict__ x, const float* __restrict__ res,
    const float* __restrict__ g1, const float* __restrict__ b1,
    const float* __restrict__ g2, const float* __restrict__ b2,
    float* __restrict__ x0, float* __restrict__ xln) {
  int row = blockIdx.x, lane = threadIdx.x;
  const float* xr = x + (size_t)row * D_;
  float v[8];
  float s = 0.f, ss = 0.f;
#pragma unroll
  for (int i = 0; i < 8; ++i) {
    float t = xr[i * 64 + lane];
    v[i] = t; s += t; ss += t * t;
  }
  s = wsum(s); ss = wsum(ss);
  float mean = s * (1.f / 512.f);
  float var = ss * (1.f / 512.f) - mean * mean;
  float rstd = rsqrtf(var + EPS_);
  float w[8];
  float s2 = 0.f, ss2 = 0.f;
#pragma unroll
  for (int i = 0; i < 8; ++i) {
    int idx = i * 64 + lane;
    float t = res[(size_t)row * D_ + idx] + (v[i] - mean) * rstd * g1[idx] + b1[idx];
    w[i] = t; s2 += t; ss2 += t * t;
  }
  s2 = wsum(s2); ss2 = wsum(ss2);
  float mean2 = s2 * (1.f / 512.f);
  float rstd2 = rsqrtf(ss2 * (1.f / 512.f) - mean2 * mean2 + EPS_);
#pragma unroll
  for (int i = 0; i < 8; ++i) {
    int idx = i * 64 + lane;
    x0[(size_t)row * D_ + idx] = w[i];
    xln[(size_t)row * D_ + idx] = (w[i] - mean2) * rstd2 * g2[idx] + b2[idx];
  }
}

// ---------------------------------------------------------------- final LN
__global__ __launch_bounds__(64) void ln_k(const float* __restrict__ x,
                                           const float* __restrict__ g,
                                           const float* __restrict__ bb,
                                           float* __restrict__ out) {
  int row = blockIdx.x, lane = threadIdx.x;
  const float* xr = x + (size_t)row * D_;
  float v[8];
  float s = 0.f, ss = 0.f;
#pragma unroll
  for (int i = 0; i < 8; ++i) {
    float t = xr[i * 64 + lane];
    v[i] = t; s += t; ss += t * t;
  }
  s = wsum(s); ss = wsum(ss);
  float mean = s * (1.f / 512.f);
  float var = ss * (1.f / 512.f) - mean * mean;
  float rstd = rsqrtf(var + EPS_);
#pragma unroll
  for (int i = 0; i < 8; ++i) {
    int idx = i * 64 + lane;
    out[(size_t)row * D_ + idx] = (v[i] - mean) * rstd * g[idx] + bb[idx];
  }
}

// ---------------------------------------------------------------- GLU
__global__ __launch_bounds__(256) void glu_k(const float* __restrict__ t1,
                                             float* __restrict__ out) {
  int t = blockIdx.x * 256 + threadIdx.x;  // BL*(D/4)
  int c4 = t & 127;
  int r = t >> 7;
  float4 a = *(const float4*)&t1[(size_t)r * (2 * D_) + c4 * 4];
  float4 g = *(const float4*)&t1[(size_t)r * (2 * D_) + D_ + c4 * 4];
  float4 o;
  o.x = a.x / (1.f + __expf(-g.x));
  o.y = a.y / (1.f + __expf(-g.y));
  o.z = a.z / (1.f + __expf(-g.z));
  o.w = a.w / (1.f + __expf(-g.w));
  *(float4*)&out[(size_t)r * D_ + c4 * 4] = o;
}

// ---------------------------------------------------------------- depthwise conv K=5 + bn + hardswish
__global__ __launch_bounds__(256) void convbn_k(
    const float* __restrict__ x, const float* __restrict__ w,
    const float* __restrict__ wb, const float* __restrict__ bng,
    const float* __restrict__ bnb, float* __restrict__ out) {
  int t = blockIdx.x * 256 + threadIdx.x;  // B*L*(D/4) = 524288
  int c4 = t & 127;
  int l = (t >> 7) & 2047;
  int b = t >> 18;
  int d0 = c4 * 4;
  float accv[4] = {0.f, 0.f, 0.f, 0.f};
#pragma unroll
  for (int kt = 0; kt < 5; ++kt) {
    int ls = l + kt - 2;
    if (ls >= 0 && ls < L_) {
      float4 xv = *(const float4*)&x[((size_t)(b * L_ + ls)) * D_ + d0];
      const float* pv = &xv.x;
#pragma unroll
      for (int j = 0; j < 4; ++j) accv[j] += pv[j] * w[(d0 + j) * 5 + kt];
    }
  }
  const float bscale = rsqrtf(1.0f + EPS_);
  float4 o;
  float* po = &o.x;
#pragma unroll
  for (int j = 0; j < 4; ++j) {
    int d = d0 + j;
    float v = accv[j] + wb[d];
    v = v * (bng[d] * bscale) + bnb[d];
    float hs = fminf(fmaxf(v + 3.f, 0.f), 6.f);
    po[j] = v * hs * (1.f / 6.f);
  }
  *(float4*)&out[((size_t)(b * L_ + l)) * D_ + d0] = o;
}

// ================================================================ launcher
extern "C" void kernel_launch(void* const* d_in, const int* in_sizes, int n_in,
                              void* d_out, int out_size, void* d_ws, size_t ws_size,
                              hipStream_t stream) {
  const float* src    = (const float*)d_in[0];
  const float* Wq     = (const float*)d_in[1];
  const float* bq     = (const float*)d_in[2];
  const float* Wk     = (const float*)d_in[3];
  const float* bk     = (const float*)d_in[4];
  const float* Wv     = (const float*)d_in[5];
  const float* bv     = (const float*)d_in[6];
  const float* Wo     = (const float*)d_in[7];
  const float* bo     = (const float*)d_in[8];
  const float* ln_g   = (const float*)d_in[9];
  const float* ln_b   = (const float*)d_in[10];
  const float* pw1_w  = (const float*)d_in[11];
  const float* pw1_b  = (const float*)d_in[12];
  const float* dw_w   = (const float*)d_in[13];
  const float* dw_b   = (const float*)d_in[14];
  const float* bn_g   = (const float*)d_in[15];
  const float* bn_b   = (const float*)d_in[16];
  const float* pw2_w  = (const float*)d_in[17];
  const float* pw2_b  = (const float*)d_in[18];
  const float* proj_w = (const float*)d_in[19];
  const float* proj_b = (const float*)d_in[20];
  const float* proj2_w= (const float*)d_in[21];
  const float* proj2_b= (const float*)d_in[22];
  const float* W1     = (const float*)d_in[23];
  const float* b1     = (const float*)d_in[24];
  const float* W2     = (const float*)d_in[25];
  const float* b2     = (const float*)d_in[26];
  const float* n1_g   = (const float*)d_in[27];
  const float* n1_b   = (const float*)d_in[28];
  const float* n2_g   = (const float*)d_in[29];
  const float* n2_b   = (const float*)d_in[30];
  float* out = (float*)d_out;

  const size_t NB = (size_t)BL_ * D_;       // 2,097,152 floats
  float* ws   = (float*)d_ws;
  float* big  = ws;                          // BL*FF = 8,388,608 floats
  float* bufA = big + (size_t)BL_ * FF_;
  float* bufB = bufA + NB;
  float* bufX0 = bufB + NB;
  float* bufC = bufX0 + NB;                  // total 16,777,216 floats = 64 MiB
  float* Qb = big;
  float* Kb = big + NB;
  float* Vb = big + 2 * NB;
  float* tab = big + 3 * NB;                 // L*32 = 65,536 floats (dead after rope)

  dim3 blk(256);
  dim3 gN512(512 / TN, BL_ / TM);            // (8,32)
  dim3 gN1024(1024 / TN, BL_ / TM);          // (16,32)
  dim3 gN2048(2048 / TN, BL_ / TM);          // (32,32)

  // RoPE table
  rope_table_k<<<(L_ * 16 + 255) / 256, blk, 0, stream>>>(tab);

  // Q, K, V projections + layout transform
  gemm_nt_k<0, 0><<<gN512, blk, 0, stream>>>(src, Wq, bq, nullptr, bufA, BL_, D_, D_);
  rope_k<<<(B_ * L_ * H_ * 16) / 256, blk, 0, stream>>>(bufA, tab, Qb);
  gemm_nt_k<0, 0><<<gN512, blk, 0, stream>>>(src, Wk, bk, nullptr, bufA, BL_, D_, D_);
  rope_k<<<(B_ * L_ * H_ * 16) / 256, blk, 0, stream>>>(bufA, tab, Kb);
  gemm_nt_k<0, 0><<<gN512, blk, 0, stream>>>(src, Wv, bv, nullptr, bufA, BL_, D_, D_);
  bhld_k<<<(B_ * L_ * D_) / 256, blk, 0, stream>>>(bufA, Vb);

  // attention -> ctx in (B,L,D)
  attn_k<<<B_ * H_ * (L_ / 256), blk, 0, stream>>>(Qb, Kb, Vb, bufA);

  // Wo
  gemm_nt_k<0, 0><<<gN512, blk, 0, stream>>>(bufA, Wo, bo, nullptr, bufB, BL_, D_, D_);

  // x0 = src + LN(attn_out); xln = LN(x0)
  ln_res_ln_k<<<BL_, 64, 0, stream>>>(bufB, src, n1_g, n1_b, ln_g, ln_b, bufX0, bufA);

  // pw1 -> GLU
  gemm_nt_k<0, 0><<<gN1024, blk, 0, stream>>>(bufA, pw1_w, pw1_b, nullptr, big, BL_, 2 * D_, D_);
  glu_k<<<(BL_ * (D_ / 4)) / 256, blk, 0, stream>>>(big, bufA);

  // depthwise conv + bn + hardswish
  convbn_k<<<(B_ * L_ * (D_ / 4)) / 256, blk, 0, stream>>>(bufA, dw_w, dw_b, bn_g, bn_b, bufB);

  // pw2 + x0 residual -> conv branch
  gemm_nt_k<0, 1><<<gN512, blk, 0, stream>>>(bufB, pw2_w, pw2_b, bufX0, bufC, BL_, D_, D_);

  // length projection: p[b] = proj_w @ x0[b] + proj_b[row]
  {
    dim3 g(512 / TN, L_ / TM, B_);           // (8,16,2)
    gemm_nn_k<<<g, blk, 0, stream>>>(proj_w, bufX0, proj_b, bufA, L_, D_, L_,
                                     (long)L_ * D_, (long)L_ * D_);
  }

  // proj2 + conv residual -> y
  gemm_nt_k<0, 1><<<gN512, blk, 0, stream>>>(bufA, proj2_w, proj2_b, bufC, bufB, BL_, D_, D_);

  // FF: gelu(y@W1^T+b1) @ W2^T + b2 + y
  gemm_nt_k<1, 0><<<gN2048, blk, 0, stream>>>(bufB, W1, b1, nullptr, big, BL_, FF_, D_);
  gemm_nt_k<0, 1><<<gN512, blk, 0, stream>>>(big, W2, b2, bufB, bufA, BL_, D_, FF_);

  // final LN -> out
  ln_k<<<BL_, 64, 0, stream>>>(bufA, n2_g, n2_b, out);
}

// Round 2
// 975.333 us; speedup vs baseline: 1.7237x; 1.7237x over previous
//
#include <hip/hip_runtime.h>
#include <math.h>

#define B_ 2
#define L_ 2048
#define D_ 512
#define H_ 16
#define HD_ 32
#define FF_ 2048
#define BL_ 4096
#define EPS_ 1e-5f

typedef unsigned short ushort;
typedef unsigned int uint;
typedef __attribute__((ext_vector_type(8))) short bf16x8;
typedef __attribute__((ext_vector_type(4))) float f32x4;

constexpr int TM = 128;
constexpr int TN = 64;
constexpr int BK = 16;

__device__ __forceinline__ ushort bf16r(float f) {
  uint u = __float_as_uint(f);
  uint r = (u + 0x7FFFu + ((u >> 16) & 1u)) >> 16;
  return (ushort)r;
}

// ---------------------------------------------------------------- wave reduce
__device__ __forceinline__ float wsum(float v) {
#pragma unroll
  for (int o = 32; o; o >>= 1) v += __shfl_xor(v, o);
  return v;
}

// ---------------------------------------------------------------- GEMM NT: C = A(M,K) @ W(N,K)^T + bias[col] (+res) (+gelu)
template <int ACT, int RES>
__global__ __launch_bounds__(256) void gemm_nt_k(
    const float* __restrict__ A, const float* __restrict__ W,
    const float* __restrict__ bias, const float* __restrict__ res,
    float* __restrict__ C, int M, int N, int Kd) {
  __shared__ float Ask[BK][TM + 4];
  __shared__ float Wsk[BK][TN + 4];
  const int tid = threadIdx.x;
  const int tx = tid & 15;
  const int ty = tid >> 4;
  const int bm = blockIdx.y * TM;
  const int bn = blockIdx.x * TN;
  float acc[8][4] = {};
  for (int k0 = 0; k0 < Kd; k0 += BK) {
    {
      int r = tid >> 1, c = (tid & 1) * 8;
      const float* ap = A + (size_t)(bm + r) * Kd + k0 + c;
      float4 a0 = *(const float4*)ap;
      float4 a1 = *(const float4*)(ap + 4);
      Ask[c + 0][r] = a0.x; Ask[c + 1][r] = a0.y; Ask[c + 2][r] = a0.z; Ask[c + 3][r] = a0.w;
      Ask[c + 4][r] = a1.x; Ask[c + 5][r] = a1.y; Ask[c + 6][r] = a1.z; Ask[c + 7][r] = a1.w;
    }
    {
      int r = tid >> 2, c = (tid & 3) * 4;
      const float* wp = W + (size_t)(bn + r) * Kd + k0 + c;
      float4 w0 = *(const float4*)wp;
      Wsk[c + 0][r] = w0.x; Wsk[c + 1][r] = w0.y; Wsk[c + 2][r] = w0.z; Wsk[c + 3][r] = w0.w;
    }
    __syncthreads();
#pragma unroll
    for (int kk = 0; kk < BK; ++kk) {
      float4 a0 = *(const float4*)&Ask[kk][ty * 4];
      float4 a1 = *(const float4*)&Ask[kk][64 + ty * 4];
      float4 w0 = *(const float4*)&Wsk[kk][tx * 4];
      float av[8] = {a0.x, a0.y, a0.z, a0.w, a1.x, a1.y, a1.z, a1.w};
      float wv[4] = {w0.x, w0.y, w0.z, w0.w};
#pragma unroll
      for (int i = 0; i < 8; ++i)
#pragma unroll
        for (int j = 0; j < 4; ++j) acc[i][j] += av[i] * wv[j];
    }
    __syncthreads();
  }
#pragma unroll
  for (int i = 0; i < 8; ++i) {
    int m = bm + ((i < 4) ? (ty * 4 + i) : (64 + ty * 4 + i - 4));
    int n = bn + tx * 4;
    float4 o;
    float* po = &o.x;
#pragma unroll
    for (int j = 0; j < 4; ++j) {
      float v = acc[i][j] + bias[n + j];
      if (RES) v += res[(size_t)m * N + n + j];
      if (ACT == 1) v = 0.5f * v * (1.0f + erff(v * 0.70710678118654752f));
      po[j] = v;
    }
    *(float4*)&C[(size_t)m * N + n] = o;
  }
}

// ---------------------------------------------------------------- GEMM NN: C = A(M,K) @ Bm(K,N) + bias[row], batched over z
__global__ __launch_bounds__(256) void gemm_nn_k(
    const float* __restrict__ A, const float* __restrict__ Bm,
    const float* __restrict__ biasRow, float* __restrict__ C,
    int M, int N, int Kd, long strideB, long strideC) {
  __shared__ float Ask[BK][TM + 4];
  __shared__ float Bsk[BK][TN + 4];
  const float* Bp = Bm + (size_t)blockIdx.z * strideB;
  float* Cp = C + (size_t)blockIdx.z * strideC;
  const int tid = threadIdx.x;
  const int tx = tid & 15;
  const int ty = tid >> 4;
  const int bm = blockIdx.y * TM;
  const int bn = blockIdx.x * TN;
  float acc[8][4] = {};
  for (int k0 = 0; k0 < Kd; k0 += BK) {
    {
      int r = tid >> 1, c = (tid & 1) * 8;
      const float* ap = A + (size_t)(bm + r) * Kd + k0 + c;
      float4 a0 = *(const float4*)ap;
      float4 a1 = *(const float4*)(ap + 4);
      Ask[c + 0][r] = a0.x; Ask[c + 1][r] = a0.y; Ask[c + 2][r] = a0.z; Ask[c + 3][r] = a0.w;
      Ask[c + 4][r] = a1.x; Ask[c + 5][r] = a1.y; Ask[c + 6][r] = a1.z; Ask[c + 7][r] = a1.w;
    }
    {
      int kr = tid >> 4, cc = (tid & 15) * 4;
      float4 b0 = *(const float4*)&Bp[(size_t)(k0 + kr) * N + bn + cc];
      *(float4*)&Bsk[kr][cc] = b0;
    }
    __syncthreads();
#pragma unroll
    for (int kk = 0; kk < BK; ++kk) {
      float4 a0 = *(const float4*)&Ask[kk][ty * 4];
      float4 a1 = *(const float4*)&Ask[kk][64 + ty * 4];
      float4 b0 = *(const float4*)&Bsk[kk][tx * 4];
      float av[8] = {a0.x, a0.y, a0.z, a0.w, a1.x, a1.y, a1.z, a1.w};
      float bv[4] = {b0.x, b0.y, b0.z, b0.w};
#pragma unroll
      for (int i = 0; i < 8; ++i)
#pragma unroll
        for (int j = 0; j < 4; ++j) acc[i][j] += av[i] * bv[j];
    }
    __syncthreads();
  }
#pragma unroll
  for (int i = 0; i < 8; ++i) {
    int m = bm + ((i < 4) ? (ty * 4 + i) : (64 + ty * 4 + i - 4));
    int n = bn + tx * 4;
    float bm_ = biasRow[m];
    float4 o;
    float* po = &o.x;
#pragma unroll
    for (int j = 0; j < 4; ++j) po[j] = acc[i][j] + bm_;
    *(float4*)&Cp[(size_t)m * N + n] = o;
  }
}

// ---------------------------------------------------------------- RoPE table (matches reference's interleaved slicing of [cos|sin])
__global__ void rope_table_k(float* __restrict__ tab) {
  int t = blockIdx.x * 256 + threadIdx.x;  // L*16
  if (t >= L_ * 16) return;
  int i = t & 15, l = t >> 4;
  float cv, sv;
  if (i < 8) {
    float inv0 = 1.0f / powf(10000.0f, (float)(2 * i) / 16.0f);
    float inv1 = 1.0f / powf(10000.0f, (float)(2 * i + 1) / 16.0f);
    cv = cosf((float)l * inv0);
    sv = cosf((float)l * inv1);
  } else {
    int ii = i - 8;
    float inv0 = 1.0f / powf(10000.0f, (float)(2 * ii) / 16.0f);
    float inv1 = 1.0f / powf(10000.0f, (float)(2 * ii + 1) / 16.0f);
    cv = sinf((float)l * inv0);
    sv = sinf((float)l * inv1);
  }
  tab[l * 32 + i] = cv;
  tab[l * 32 + 16 + i] = sv;
}

// ---------------------------------------------------------------- rope + (B,L,D)->(B,H,L,HD)
__global__ __launch_bounds__(256) void rope_k(const float* __restrict__ xin,
                                              const float* __restrict__ tab,
                                              float* __restrict__ out) {
  int t = blockIdx.x * 256 + threadIdx.x;  // B*L*H*16 = 1048576
  int i = t & 15;
  int h = (t >> 4) & 15;
  int l = (t >> 8) & 2047;
  int b = t >> 19;
  const float* xp = xin + ((size_t)(b * L_ + l)) * D_ + h * HD_;
  float xe = xp[2 * i], xo = xp[2 * i + 1];
  float cv = tab[l * 32 + i], sv = tab[l * 32 + 16 + i];
  float* op = out + (((size_t)(b * H_ + h)) * L_ + l) * HD_;
  op[i] = xe * cv - xo * sv;
  op[16 + i] = xe * sv + xo * cv;
}

// ---------------------------------------------------------------- plain (B,L,D)->(B,H,L,HD)
__global__ __launch_bounds__(256) void bhld_k(const float* __restrict__ xin,
                                              float* __restrict__ out) {
  int t = blockIdx.x * 256 + threadIdx.x;  // B*L*D = 2097152
  int d = t & 31;
  int h = (t >> 5) & 15;
  int l = (t >> 9) & 2047;
  int b = t >> 20;
  out[(((size_t)(b * H_ + h)) * L_ + l) * HD_ + d] =
      xin[((size_t)(b * L_ + l)) * D_ + h * HD_ + d];
}

// ---------------------------------------------------------------- MFMA flash attention (bf16 mma, f32 softmax)
// block: 256 thr = 4 waves, 64 queries/block (16/wave). KV tiles of 128.
__global__ __launch_bounds__(256) void attn_mfma_k(const float* __restrict__ q,
                                                   const float* __restrict__ k,
                                                   const float* __restrict__ v,
                                                   float* __restrict__ ctx) {
  __shared__ __align__(16) ushort K_lds[4][130][8];   // [dim-slot][key][8 bf16], padded
  __shared__ __align__(16) ushort V_lds[32][136];     // [dim][key' interleaved], padded
  __shared__ __align__(16) uint P_lds[4][4][16][4];   // [wave][slot][q][4 words]
  const int tid = threadIdx.x;
  const int wid = tid >> 6, lane = tid & 63;
  const int s = lane >> 4, lr = lane & 15;
  const int bh = blockIdx.x >> 5;
  const int qb = (blockIdx.x & 31) * 64;
  const int h = bh & 15, bidx = bh >> 4;
  const float slope = exp2f(-0.5f * (float)h);
  const float scale = 0.1767766952966369f;  // 32^-0.5

  // Q fragment: lane holds Q[q=lr][d = s*8+j], pre-scaled
  const int qrow = qb + wid * 16 + lr;
  bf16x8 qa;
  {
    const float* qp = q + ((size_t)bh * L_ + qrow) * HD_ + s * 8;
    float4 a = *(const float4*)qp;
    float4 b = *(const float4*)(qp + 4);
    qa[0] = (short)bf16r(a.x * scale); qa[1] = (short)bf16r(a.y * scale);
    qa[2] = (short)bf16r(a.z * scale); qa[3] = (short)bf16r(a.w * scale);
    qa[4] = (short)bf16r(b.x * scale); qa[5] = (short)bf16r(b.y * scale);
    qa[6] = (short)bf16r(b.z * scale); qa[7] = (short)bf16r(b.w * scale);
  }

  float mval[4], lsum[4];
#pragma unroll
  for (int r = 0; r < 4; ++r) { mval[r] = -1e30f; lsum[r] = 0.f; }
  f32x4 acc0 = {0.f, 0.f, 0.f, 0.f}, acc1 = {0.f, 0.f, 0.f, 0.f};
  const float* kg = k + (size_t)bh * L_ * HD_;
  const float* vg = v + (size_t)bh * L_ * HD_;

  for (int t0 = 0; t0 < L_; t0 += 128) {
    __syncthreads();
    // ---- stage K tile: 128 keys x 32 dims -> bf16, slot-major
#pragma unroll
    for (int pass = 0; pass < 2; ++pass) {
      int id = tid + pass * 256;
      int key = id >> 2, slot = id & 3;
      const float* gp = kg + (size_t)(t0 + key) * HD_ + slot * 8;
      float4 a = *(const float4*)gp;
      float4 b = *(const float4*)(gp + 4);
      bf16x8 kv;
      kv[0] = (short)bf16r(a.x); kv[1] = (short)bf16r(a.y);
      kv[2] = (short)bf16r(a.z); kv[3] = (short)bf16r(a.w);
      kv[4] = (short)bf16r(b.x); kv[5] = (short)bf16r(b.y);
      kv[6] = (short)bf16r(b.z); kv[7] = (short)bf16r(b.w);
      *(bf16x8*)&K_lds[slot][key][0] = kv;
    }
    // ---- stage V tile transposed+interleaved: V_lds[d][key'] with key'=2*kk(+1) for kk,kk+16
    {
      int chunk = lane >> 4, kk = lane & 15, dg = wid;
      const float* g0 = vg + (size_t)(t0 + chunk * 32 + kk) * HD_ + dg * 8;
      const float* g1 = g0 + 16 * HD_;
      float4 a0 = *(const float4*)g0, a1 = *(const float4*)(g0 + 4);
      float4 b0 = *(const float4*)g1, b1 = *(const float4*)(g1 + 4);
      float va[8] = {a0.x, a0.y, a0.z, a0.w, a1.x, a1.y, a1.z, a1.w};
      float vb[8] = {b0.x, b0.y, b0.z, b0.w, b1.x, b1.y, b1.z, b1.w};
#pragma unroll
      for (int i = 0; i < 8; ++i) {
        int d = dg * 8 + i;
        uint w = (uint)bf16r(va[i]) | ((uint)bf16r(vb[i]) << 16);
        *(uint*)&V_lds[d][chunk * 32 + kk * 2] = w;
      }
    }
    __syncthreads();

    // ---- QK^T: 8 MFMAs (128 keys); D[m=q][n=key]
    f32x4 sc[8];
#pragma unroll
    for (int c = 0; c < 8; ++c) {
      bf16x8 kf = *(const bf16x8*)&K_lds[s][c * 16 + lr][0];
      f32x4 z = {0.f, 0.f, 0.f, 0.f};
      sc[c] = __builtin_amdgcn_mfma_f32_16x16x32_bf16(qa, kf, z, 0, 0, 0);
    }
    // ---- ALiBi + online softmax (per q-row r, reduce over 16-lane group)
#pragma unroll
    for (int r = 0; r < 4; ++r) {
      int qg = qb + wid * 16 + s * 4 + r;
#pragma unroll
      for (int c = 0; c < 8; ++c) {
        int dist = qg - (t0 + c * 16 + lr);
        sc[c][r] += (dist > 0) ? slope * (float)dist : 0.f;
      }
      float rm = sc[0][r];
#pragma unroll
      for (int c = 1; c < 8; ++c) rm = fmaxf(rm, sc[c][r]);
      rm = fmaxf(rm, __shfl_xor(rm, 1));
      rm = fmaxf(rm, __shfl_xor(rm, 2));
      rm = fmaxf(rm, __shfl_xor(rm, 4));
      rm = fmaxf(rm, __shfl_xor(rm, 8));
      float nm = fmaxf(mval[r], rm);
      float corr = __expf(mval[r] - nm);
      mval[r] = nm;
      float rs = 0.f;
#pragma unroll
      for (int c = 0; c < 8; ++c) {
        float p = __expf(sc[c][r] - nm);
        sc[c][r] = p;
        rs += p;
      }
      rs += __shfl_xor(rs, 1);
      rs += __shfl_xor(rs, 2);
      rs += __shfl_xor(rs, 4);
      rs += __shfl_xor(rs, 8);
      lsum[r] = lsum[r] * corr + rs;
      acc0[r] *= corr;
      acc1[r] *= corr;
    }
    // ---- PV: 4 chunks of 32 keys, P through LDS (interleaved key order shared with V)
#pragma unroll
    for (int t = 0; t < 4; ++t) {
#pragma unroll
      for (int r = 0; r < 4; ++r) {
        uint w = (uint)bf16r(sc[2 * t][r]) | ((uint)bf16r(sc[2 * t + 1][r]) << 16);
        P_lds[wid][lr >> 2][s * 4 + r][lr & 3] = w;
      }
      asm volatile("s_waitcnt lgkmcnt(0)" ::: "memory");
      bf16x8 pf = *(const bf16x8*)&P_lds[wid][s][lr][0];
      bf16x8 v0 = *(const bf16x8*)&V_lds[lr][t * 32 + s * 8];
      bf16x8 v1 = *(const bf16x8*)&V_lds[16 + lr][t * 32 + s * 8];
      acc0 = __builtin_amdgcn_mfma_f32_16x16x32_bf16(pf, v0, acc0, 0, 0, 0);
      acc1 = __builtin_amdgcn_mfma_f32_16x16x32_bf16(pf, v1, acc1, 0, 0, 0);
    }
  }
  // ---- epilogue: ctx[b, q, h*32 + d] = acc/lsum
#pragma unroll
  for (int r = 0; r < 4; ++r) {
    int qg = qb + wid * 16 + s * 4 + r;
    float il = 1.f / lsum[r];
    float* op = ctx + ((size_t)(bidx * L_ + qg)) * D_ + h * HD_;
    op[lr] = acc0[r] * il;
    op[16 + lr] = acc1[r] * il;
  }
}

// ---------------------------------------------------------------- x0 = res + LN(x; g1,b1), xln = LN(x0; g2,b2)
__global__ __launch_bounds__(64) void ln_res_ln_k(
    const float* __restrict__ x, const float* __restrict__ res,
    const float* __restrict__ g1, const float* __restrict__ b1,
    const float* __restrict__ g2, const float* __restrict__ b2,
    float* __restrict__ x0, float* __restrict__ xln) {
  int row = blockIdx.x, lane = threadIdx.x;
  const float* xr = x + (size_t)row * D_;
  float v[8];
  float s = 0.f, ss = 0.f;
#pragma unroll
  for (int i = 0; i < 8; ++i) {
    float t = xr[i * 64 + lane];
    v[i] = t; s += t; ss += t * t;
  }
  s = wsum(s); ss = wsum(ss);
  float mean = s * (1.f / 512.f);
  float var = ss * (1.f / 512.f) - mean * mean;
  float rstd = rsqrtf(var + EPS_);
  float w[8];
  float s2 = 0.f, ss2 = 0.f;
#pragma unroll
  for (int i = 0; i < 8; ++i) {
    int idx = i * 64 + lane;
    float t = res[(size_t)row * D_ + idx] + (v[i] - mean) * rstd * g1[idx] + b1[idx];
    w[i] = t; s2 += t; ss2 += t * t;
  }
  s2 = wsum(s2); ss2 = wsum(ss2);
  float mean2 = s2 * (1.f / 512.f);
  float rstd2 = rsqrtf(ss2 * (1.f / 512.f) - mean2 * mean2 + EPS_);
#pragma unroll
  for (int i = 0; i < 8; ++i) {
    int idx = i * 64 + lane;
    x0[(size_t)row * D_ + idx] = w[i];
    xln[(size_t)row * D_ + idx] = (w[i] - mean2) * rstd2 * g2[idx] + b2[idx];
  }
}

// ---------------------------------------------------------------- final LN
__global__ __launch_bounds__(64) void ln_k(const float* __restrict__ x,
                                           const float* __restrict__ g,
                                           const float* __restrict__ bb,
                                           float* __restrict__ out) {
  int row = blockIdx.x, lane = threadIdx.x;
  const float* xr = x + (size_t)row * D_;
  float v[8];
  float s = 0.f, ss = 0.f;
#pragma unroll
  for (int i = 0; i < 8; ++i) {
    float t = xr[i * 64 + lane];
    v[i] = t; s += t; ss += t * t;
  }
  s = wsum(s); ss = wsum(ss);
  float mean = s * (1.f / 512.f);
  float var = ss * (1.f / 512.f) - mean * mean;
  float rstd = rsqrtf(var + EPS_);
#pragma unroll
  for (int i = 0; i < 8; ++i) {
    int idx = i * 64 + lane;
    out[(size_t)row * D_ + idx] = (v[i] - mean) * rstd * g[idx] + bb[idx];
  }
}

// ---------------------------------------------------------------- GLU
__global__ __launch_bounds__(256) void glu_k(const float* __restrict__ t1,
                                             float* __restrict__ out) {
  int t = blockIdx.x * 256 + threadIdx.x;  // BL*(D/4)
  int c4 = t & 127;
  int r = t >> 7;
  float4 a = *(const float4*)&t1[(size_t)r * (2 * D_) + c4 * 4];
  float4 g = *(const float4*)&t1[(size_t)r * (2 * D_) + D_ + c4 * 4];
  float4 o;
  o.x = a.x / (1.f + __expf(-g.x));
  o.y = a.y / (1.f + __expf(-g.y));
  o.z = a.z / (1.f + __expf(-g.z));
  o.w = a.w / (1.f + __expf(-g.w));
  *(float4*)&out[(size_t)r * D_ + c4 * 4] = o;
}

// ---------------------------------------------------------------- depthwise conv K=5 + bn + hardswish
__global__ __launch_bounds__(256) void convbn_k(
    const float* __restrict__ x, const float* __restrict__ w,
    const float* __restrict__ wb, const float* __restrict__ bng,
    const float* __restrict__ bnb, float* __restrict__ out) {
  int t = blockIdx.x * 256 + threadIdx.x;  // B*L*(D/4) = 524288
  int c4 = t & 127;
  int l = (t >> 7) & 2047;
  int b = t >> 18;
  int d0 = c4 * 4;
  float accv[4] = {0.f, 0.f, 0.f, 0.f};
#pragma unroll
  for (int kt = 0; kt < 5; ++kt) {
    int ls = l + kt - 2;
    if (ls >= 0 && ls < L_) {
      float4 xv = *(const float4*)&x[((size_t)(b * L_ + ls)) * D_ + d0];
      const float* pv = &xv.x;
#pragma unroll
      for (int j = 0; j < 4; ++j) accv[j] += pv[j] * w[(d0 + j) * 5 + kt];
    }
  }
  const float bscale = rsqrtf(1.0f + EPS_);
  float4 o;
  float* po = &o.x;
#pragma unroll
  for (int j = 0; j < 4; ++j) {
    int d = d0 + j;
    float v = accv[j] + wb[d];
    v = v * (bng[d] * bscale) + bnb[d];
    float hs = fminf(fmaxf(v + 3.f, 0.f), 6.f);
    po[j] = v * hs * (1.f / 6.f);
  }
  *(float4*)&out[((size_t)(b * L_ + l)) * D_ + d0] = o;
}

// ================================================================ launcher
extern "C" void kernel_launch(void* const* d_in, const int* in_sizes, int n_in,
                              void* d_out, int out_size, void* d_ws, size_t ws_size,
                              hipStream_t stream) {
  const float* src    = (const float*)d_in[0];
  const float* Wq     = (const float*)d_in[1];
  const float* bq     = (const float*)d_in[2];
  const float* Wk     = (const float*)d_in[3];
  const float* bk     = (const float*)d_in[4];
  const float* Wv     = (const float*)d_in[5];
  const float* bv     = (const float*)d_in[6];
  const float* Wo     = (const float*)d_in[7];
  const float* bo     = (const float*)d_in[8];
  const float* ln_g   = (const float*)d_in[9];
  const float* ln_b   = (const float*)d_in[10];
  const float* pw1_w  = (const float*)d_in[11];
  const float* pw1_b  = (const float*)d_in[12];
  const float* dw_w   = (const float*)d_in[13];
  const float* dw_b   = (const float*)d_in[14];
  const float* bn_g   = (const float*)d_in[15];
  const float* bn_b   = (const float*)d_in[16];
  const float* pw2_w  = (const float*)d_in[17];
  const float* pw2_b  = (const float*)d_in[18];
  const float* proj_w = (const float*)d_in[19];
  const float* proj_b = (const float*)d_in[20];
  const float* proj2_w= (const float*)d_in[21];
  const float* proj2_b= (const float*)d_in[22];
  const float* W1     = (const float*)d_in[23];
  const float* b1     = (const float*)d_in[24];
  const float* W2     = (const float*)d_in[25];
  const float* b2     = (const float*)d_in[26];
  const float* n1_g   = (const float*)d_in[27];
  const float* n1_b   = (const float*)d_in[28];
  const float* n2_g   = (const float*)d_in[29];
  const float* n2_b   = (const float*)d_in[30];
  float* out = (float*)d_out;

  const size_t NB = (size_t)BL_ * D_;       // 2,097,152 floats
  float* ws   = (float*)d_ws;
  float* big  = ws;                          // BL*FF = 8,388,608 floats
  float* bufA = big + (size_t)BL_ * FF_;
  float* bufB = bufA + NB;
  float* bufX0 = bufB + NB;
  float* bufC = bufX0 + NB;                  // total 16,777,216 floats = 64 MiB
  float* Qb = big;
  float* Kb = big + NB;
  float* Vb = big + 2 * NB;
  float* tab = big + 3 * NB;                 // L*32 floats (dead after rope)

  dim3 blk(256);
  dim3 gN512(512 / TN, BL_ / TM);            // (8,32)
  dim3 gN1024(1024 / TN, BL_ / TM);          // (16,32)
  dim3 gN2048(2048 / TN, BL_ / TM);          // (32,32)

  // RoPE table
  rope_table_k<<<(L_ * 16 + 255) / 256, blk, 0, stream>>>(tab);

  // Q, K, V projections + layout transform
  gemm_nt_k<0, 0><<<gN512, blk, 0, stream>>>(src, Wq, bq, nullptr, bufA, BL_, D_, D_);
  rope_k<<<(B_ * L_ * H_ * 16) / 256, blk, 0, stream>>>(bufA, tab, Qb);
  gemm_nt_k<0, 0><<<gN512, blk, 0, stream>>>(src, Wk, bk, nullptr, bufA, BL_, D_, D_);
  rope_k<<<(B_ * L_ * H_ * 16) / 256, blk, 0, stream>>>(bufA, tab, Kb);
  gemm_nt_k<0, 0><<<gN512, blk, 0, stream>>>(src, Wv, bv, nullptr, bufA, BL_, D_, D_);
  bhld_k<<<(B_ * L_ * D_) / 256, blk, 0, stream>>>(bufA, Vb);

  // MFMA flash attention -> ctx in (B,L,D)
  attn_mfma_k<<<B_ * H_ * (L_ / 64), blk, 0, stream>>>(Qb, Kb, Vb, bufA);

  // Wo
  gemm_nt_k<0, 0><<<gN512, blk, 0, stream>>>(bufA, Wo, bo, nullptr, bufB, BL_, D_, D_);

  // x0 = src + LN(attn_out); xln = LN(x0)
  ln_res_ln_k<<<BL_, 64, 0, stream>>>(bufB, src, n1_g, n1_b, ln_g, ln_b, bufX0, bufA);

  // pw1 -> GLU
  gemm_nt_k<0, 0><<<gN1024, blk, 0, stream>>>(bufA, pw1_w, pw1_b, nullptr, big, BL_, 2 * D_, D_);
  glu_k<<<(BL_ * (D_ / 4)) / 256, blk, 0, stream>>>(big, bufA);

  // depthwise conv + bn + hardswish
  convbn_k<<<(B_ * L_ * (D_ / 4)) / 256, blk, 0, stream>>>(bufA, dw_w, dw_b, bn_g, bn_b, bufB);

  // pw2 + x0 residual -> conv branch
  gemm_nt_k<0, 1><<<gN512, blk, 0, stream>>>(bufB, pw2_w, pw2_b, bufX0, bufC, BL_, D_, D_);

  // length projection: p[b] = proj_w @ x0[b] + proj_b[row]
  {
    dim3 g(512 / TN, L_ / TM, B_);           // (8,16,2)
    gemm_nn_k<<<g, blk, 0, stream>>>(proj_w, bufX0, proj_b, bufA, L_, D_, L_,
                                     (long)L_ * D_, (long)L_ * D_);
  }

  // proj2 + conv residual -> y
  gemm_nt_k<0, 1><<<gN512, blk, 0, stream>>>(bufA, proj2_w, proj2_b, bufC, bufB, BL_, D_, D_);

  // FF: gelu(y@W1^T+b1) @ W2^T + b2 + y
  gemm_nt_k<1, 0><<<gN2048, blk, 0, stream>>>(bufB, W1, b1, nullptr, big, BL_, FF_, D_);
  gemm_nt_k<0, 1><<<gN512, blk, 0, stream>>>(big, W2, b2, bufB, bufA, BL_, D_, FF_);

  // final LN -> out
  ln_k<<<BL_, 64, 0, stream>>>(bufA, n2_g, n2_b, out);
}

// Round 3
// 362.668 us; speedup vs baseline: 4.6356x; 2.6893x over previous
//
#include <hip/hip_runtime.h>
#include <math.h>

#define B_ 2
#define L_ 2048
#define D_ 512
#define H_ 16
#define HD_ 32
#define FF_ 2048
#define BL_ 4096
#define EPS_ 1e-5f

typedef unsigned short ushort;
typedef unsigned int uint;
typedef __attribute__((ext_vector_type(8))) short bf16x8;
typedef __attribute__((ext_vector_type(4))) float f32x4;

__device__ __forceinline__ ushort bf16r(float f) {
  uint u = __float_as_uint(f);
  uint r = (u + 0x7FFFu + ((u >> 16) & 1u)) >> 16;
  return (ushort)r;
}
__device__ __forceinline__ float bf2f(uint u) { return __uint_as_float(u << 16); }

__device__ __forceinline__ float wsum(float v) {
#pragma unroll
  for (int o = 32; o; o >>= 1) v += __shfl_xor(v, o);
  return v;
}

__device__ __forceinline__ void gload16(const void* g, void* l) {
  __builtin_amdgcn_global_load_lds(
      (const __attribute__((address_space(1))) void*)g,
      (__attribute__((address_space(3))) void*)l, 16, 0, 0);
}

// ================================================================ bf16 MFMA GEMM
// C[m,n] = epi( sum_k A[m,k] * W[n,k] )
// EPI=0: generic (BROW: bias[m] vs bias[n]; GELU; RES: +res; OUTF/OUTB)
// EPI=1: QKV+RoPE epilogue -> Qb/Kb/Vb bf16 (B,H,L,HD)
template <int EPI, int BROW, int GELU, int RES, int OUTF, int OUTB>
__global__ __launch_bounds__(256, 2) void gemm_bf_k(
    const ushort* __restrict__ A, const ushort* __restrict__ W,
    const float* __restrict__ bias, const float* __restrict__ res,
    float* __restrict__ Cf, ushort* __restrict__ Cb,
    const int M, const int N, const int Kd, const long sW, const long sC,
    const float* __restrict__ tab, ushort* __restrict__ Qb,
    ushort* __restrict__ Kb, ushort* __restrict__ Vb) {
  __shared__ __align__(16) ushort As[128 * 64];
  __shared__ __align__(16) ushort Ws[128 * 64];
  const int tid = threadIdx.x;
  const int wid = tid >> 6, lane = tid & 63;
  const int wm = wid >> 1, wn = wid & 1;
  const int lane15 = lane & 15, lgrp = lane >> 4;
  const int bm = blockIdx.y * 128, bn = blockIdx.x * 128;
  const int z = blockIdx.z;
  const ushort* Wz = W + (size_t)z * sW;

  f32x4 acc[4][4];
#pragma unroll
  for (int i = 0; i < 4; ++i)
#pragma unroll
    for (int j = 0; j < 4; ++j) acc[i][j] = (f32x4){0.f, 0.f, 0.f, 0.f};

  for (int k0 = 0; k0 < Kd; k0 += 64) {
    __syncthreads();
#pragma unroll
    for (int i = 0; i < 4; ++i) {
      const int cb = i * 256 + wid * 64;
      const int chunk = cb + lane;
      const int ml = chunk >> 3;
      const int c16 = (chunk & 7) ^ (ml & 7);  // inverse-swizzled source slot
      gload16(A + (size_t)(bm + ml) * Kd + k0 + c16 * 8, &As[(size_t)cb * 8]);
      gload16(Wz + (size_t)(bn + ml) * Kd + k0 + c16 * 8, &Ws[(size_t)cb * 8]);
    }
    __syncthreads();

    bf16x8 af[2][4], wf[2][4];
#pragma unroll
    for (int kk = 0; kk < 2; ++kk)
#pragma unroll
      for (int f = 0; f < 4; ++f) {
        const int ma = wm * 64 + f * 16 + lane15;
        const int ca = (kk * 4 + lgrp) ^ (ma & 7);
        af[kk][f] = *(const bf16x8*)&As[ma * 64 + ca * 8];
        const int nb = wn * 64 + f * 16 + lane15;
        const int cw = (kk * 4 + lgrp) ^ (nb & 7);
        wf[kk][f] = *(const bf16x8*)&Ws[nb * 64 + cw * 8];
      }
#pragma unroll
    for (int kk = 0; kk < 2; ++kk)
#pragma unroll
      for (int fm = 0; fm < 4; ++fm)
#pragma unroll
        for (int fn = 0; fn < 4; ++fn)
          acc[fm][fn] = __builtin_amdgcn_mfma_f32_16x16x32_bf16(
              af[kk][fm], wf[kk][fn], acc[fm][fn], 0, 0, 0);
  }

#pragma unroll
  for (int fm = 0; fm < 4; ++fm) {
#pragma unroll
    for (int fn = 0; fn < 4; ++fn) {
      const int n = bn + wn * 64 + fn * 16 + lane15;
      float bcol = 0.f;
      if (EPI == 1 || !BROW) bcol = bias[n];
#pragma unroll
      for (int r = 0; r < 4; ++r) {
        const int m = bm + wm * 64 + fm * 16 + lgrp * 4 + r;
        float val = acc[fm][fn][r];
        if (EPI == 1) {
          val += bcol;
          float p = __shfl_xor(val, 1);
          const int l = m & 2047, b = m >> 11;
          const int h = (n >> 5) & 15;
          if (n < 1024) {
            const int ch = n & 31, i2 = ch >> 1;
            const float cv = tab[l * 32 + i2], sv = tab[l * 32 + 16 + i2];
            const float o = (ch & 1) ? (p * sv + val * cv) : (val * cv - p * sv);
            const int dcol = (ch & 1) ? 16 + i2 : i2;
            if (n < 512)
              Qb[(((size_t)(b * 16 + h)) * 2048 + l) * 32 + dcol] =
                  bf16r(o * 0.1767766952966369f);
            else
              Kb[(((size_t)(b * 16 + h)) * 2048 + l) * 32 + dcol] = bf16r(o);
          } else {
            Vb[(((size_t)(b * 16 + h)) * 2048 + l) * 32 + (n & 31)] = bf16r(val);
          }
        } else {
          val += BROW ? bias[m] : bcol;
          if (RES) val += res[(size_t)z * sC + (size_t)m * N + n];
          if (GELU) val = 0.5f * val * (1.f + erff(val * 0.70710678118654752f));
          const size_t o = (size_t)z * sC + (size_t)m * N + n;
          if (OUTF) Cf[o] = val;
          if (OUTB) Cb[o] = bf16r(val);
        }
      }
    }
  }
}

// ================================================================ weight/src -> bf16 conversion (11 segments)
struct CvtArgs {
  const float* s[11];
  ushort* d[11];
  int n[11];
};
__global__ __launch_bounds__(256) void cvt_all_k(CvtArgs a) {
  const int seg = blockIdx.y;
  const int n = a.n[seg];
  const int i = (blockIdx.x * 256 + threadIdx.x) * 8;
  if (i >= n) return;
  const float* s = a.s[seg] + i;
  float4 x = *(const float4*)s, y = *(const float4*)(s + 4);
  bf16x8 o;
  o[0] = (short)bf16r(x.x); o[1] = (short)bf16r(x.y);
  o[2] = (short)bf16r(x.z); o[3] = (short)bf16r(x.w);
  o[4] = (short)bf16r(y.x); o[5] = (short)bf16r(y.y);
  o[6] = (short)bf16r(y.z); o[7] = (short)bf16r(y.w);
  *(bf16x8*)(a.d[seg] + i) = o;
}

// ---------------------------------------------------------------- RoPE table
__global__ void rope_table_k(float* __restrict__ tab) {
  int t = blockIdx.x * 256 + threadIdx.x;
  if (t >= L_ * 16) return;
  int i = t & 15, l = t >> 4;
  float cv, sv;
  if (i < 8) {
    float inv0 = 1.0f / powf(10000.0f, (float)(2 * i) / 16.0f);
    float inv1 = 1.0f / powf(10000.0f, (float)(2 * i + 1) / 16.0f);
    cv = cosf((float)l * inv0);
    sv = cosf((float)l * inv1);
  } else {
    int ii = i - 8;
    float inv0 = 1.0f / powf(10000.0f, (float)(2 * ii) / 16.0f);
    float inv1 = 1.0f / powf(10000.0f, (float)(2 * ii + 1) / 16.0f);
    cv = sinf((float)l * inv0);
    sv = sinf((float)l * inv1);
  }
  tab[l * 32 + i] = cv;
  tab[l * 32 + 16 + i] = sv;
}

// ---------------------------------------------------------------- transpose x0 f32 -> x0T bf16 (B,D,L)
__global__ __launch_bounds__(256) void transp_k(const float* __restrict__ x,
                                                ushort* __restrict__ xT) {
  __shared__ float t[32][33];
  const int b = blockIdx.z, l0 = blockIdx.x * 32, d0 = blockIdx.y * 32;
  const int tx = threadIdx.x & 31, ty = threadIdx.x >> 5;
#pragma unroll
  for (int i = 0; i < 4; ++i)
    t[ty + i * 8][tx] = x[((size_t)(b * L_ + l0 + ty + i * 8)) * D_ + d0 + tx];
  __syncthreads();
#pragma unroll
  for (int i = 0; i < 4; ++i)
    xT[((size_t)(b * D_ + d0 + ty + i * 8)) * L_ + l0 + tx] =
        bf16r(t[tx][ty + i * 8]);
}

// ---------------------------------------------------------------- MFMA flash attention (bf16 in/out)
__global__ __launch_bounds__(256) void attn_mfma_k(const ushort* __restrict__ q,
                                                   const ushort* __restrict__ k,
                                                   const ushort* __restrict__ v,
                                                   ushort* __restrict__ ctx) {
  __shared__ __align__(16) ushort K_lds[4][130][8];
  __shared__ __align__(16) ushort V_lds[32][136];
  __shared__ __align__(16) uint P_lds[4][4][16][4];
  const int tid = threadIdx.x;
  const int wid = tid >> 6, lane = tid & 63;
  const int s = lane >> 4, lr = lane & 15;
  const int bh = blockIdx.x >> 5;
  const int qb = (blockIdx.x & 31) * 64;
  const int h = bh & 15, bidx = bh >> 4;
  const float slope = exp2f(-0.5f * (float)h);

  const int qrow = qb + wid * 16 + lr;
  bf16x8 qa = *(const bf16x8*)&q[((size_t)bh * L_ + qrow) * HD_ + s * 8];

  float mval[4], lsum[4];
#pragma unroll
  for (int r = 0; r < 4; ++r) { mval[r] = -1e30f; lsum[r] = 0.f; }
  f32x4 acc0 = {0.f, 0.f, 0.f, 0.f}, acc1 = {0.f, 0.f, 0.f, 0.f};
  const ushort* kg = k + (size_t)bh * L_ * HD_;
  const ushort* vg = v + (size_t)bh * L_ * HD_;

  for (int t0 = 0; t0 < L_; t0 += 128) {
    __syncthreads();
#pragma unroll
    for (int pass = 0; pass < 2; ++pass) {
      int id = tid + pass * 256;
      int key = id >> 2, slot = id & 3;
      bf16x8 kv = *(const bf16x8*)&kg[(size_t)(t0 + key) * HD_ + slot * 8];
      *(bf16x8*)&K_lds[slot][key][0] = kv;
    }
    {
      int chunk = lane >> 4, kk = lane & 15, dg = wid;
      const ushort* g0 = vg + (size_t)(t0 + chunk * 32 + kk) * HD_ + dg * 8;
      bf16x8 va = *(const bf16x8*)g0;
      bf16x8 vb = *(const bf16x8*)(g0 + 16 * HD_);
#pragma unroll
      for (int i = 0; i < 8; ++i) {
        uint w = ((uint)(ushort)va[i]) | (((uint)(ushort)vb[i]) << 16);
        *(uint*)&V_lds[dg * 8 + i][chunk * 32 + kk * 2] = w;
      }
    }
    __syncthreads();

    f32x4 sc[8];
#pragma unroll
    for (int c = 0; c < 8; ++c) {
      bf16x8 kf = *(const bf16x8*)&K_lds[s][c * 16 + lr][0];
      f32x4 zz = {0.f, 0.f, 0.f, 0.f};
      sc[c] = __builtin_amdgcn_mfma_f32_16x16x32_bf16(qa, kf, zz, 0, 0, 0);
    }
#pragma unroll
    for (int r = 0; r < 4; ++r) {
      int qg = qb + wid * 16 + s * 4 + r;
#pragma unroll
      for (int c = 0; c < 8; ++c) {
        int dist = qg - (t0 + c * 16 + lr);
        sc[c][r] += (dist > 0) ? slope * (float)dist : 0.f;
      }
      float rm = sc[0][r];
#pragma unroll
      for (int c = 1; c < 8; ++c) rm = fmaxf(rm, sc[c][r]);
      rm = fmaxf(rm, __shfl_xor(rm, 1));
      rm = fmaxf(rm, __shfl_xor(rm, 2));
      rm = fmaxf(rm, __shfl_xor(rm, 4));
      rm = fmaxf(rm, __shfl_xor(rm, 8));
      float nm = fmaxf(mval[r], rm);
      float corr = __expf(mval[r] - nm);
      mval[r] = nm;
      float rs = 0.f;
#pragma unroll
      for (int c = 0; c < 8; ++c) {
        float p = __expf(sc[c][r] - nm);
        sc[c][r] = p;
        rs += p;
      }
      rs += __shfl_xor(rs, 1);
      rs += __shfl_xor(rs, 2);
      rs += __shfl_xor(rs, 4);
      rs += __shfl_xor(rs, 8);
      lsum[r] = lsum[r] * corr + rs;
      acc0[r] *= corr;
      acc1[r] *= corr;
    }
#pragma unroll
    for (int t = 0; t < 4; ++t) {
#pragma unroll
      for (int r = 0; r < 4; ++r) {
        uint w = (uint)bf16r(sc[2 * t][r]) | ((uint)bf16r(sc[2 * t + 1][r]) << 16);
        P_lds[wid][lr >> 2][s * 4 + r][lr & 3] = w;
      }
      asm volatile("s_waitcnt lgkmcnt(0)" ::: "memory");
      bf16x8 pf = *(const bf16x8*)&P_lds[wid][s][lr][0];
      bf16x8 v0 = *(const bf16x8*)&V_lds[lr][t * 32 + s * 8];
      bf16x8 v1 = *(const bf16x8*)&V_lds[16 + lr][t * 32 + s * 8];
      acc0 = __builtin_amdgcn_mfma_f32_16x16x32_bf16(pf, v0, acc0, 0, 0, 0);
      acc1 = __builtin_amdgcn_mfma_f32_16x16x32_bf16(pf, v1, acc1, 0, 0, 0);
    }
  }
#pragma unroll
  for (int r = 0; r < 4; ++r) {
    int qg = qb + wid * 16 + s * 4 + r;
    float il = 1.f / lsum[r];
    ushort* op = ctx + ((size_t)(bidx * L_ + qg)) * D_ + h * HD_;
    op[lr] = bf16r(acc0[r] * il);
    op[16 + lr] = bf16r(acc1[r] * il);
  }
}

// ---------------------------------------------------------------- x0 = res + LN(x), xln_bf = LN(x0)
__global__ __launch_bounds__(64) void ln_res_ln_k(
    const float* __restrict__ x, const float* __restrict__ res,
    const float* __restrict__ g1, const float* __restrict__ b1,
    const float* __restrict__ g2, const float* __restrict__ b2,
    float* __restrict__ x0, ushort* __restrict__ xln) {
  int row = blockIdx.x, lane = threadIdx.x;
  const float* xr = x + (size_t)row * D_;
  float v[8];
  float s = 0.f, ss = 0.f;
#pragma unroll
  for (int i = 0; i < 8; ++i) {
    float t = xr[i * 64 + lane];
    v[i] = t; s += t; ss += t * t;
  }
  s = wsum(s); ss = wsum(ss);
  float mean = s * (1.f / 512.f);
  float rstd = rsqrtf(ss * (1.f / 512.f) - mean * mean + EPS_);
  float w[8];
  float s2 = 0.f, ss2 = 0.f;
#pragma unroll
  for (int i = 0; i < 8; ++i) {
    int idx = i * 64 + lane;
    float t = res[(size_t)row * D_ + idx] + (v[i] - mean) * rstd * g1[idx] + b1[idx];
    w[i] = t; s2 += t; ss2 += t * t;
  }
  s2 = wsum(s2); ss2 = wsum(ss2);
  float mean2 = s2 * (1.f / 512.f);
  float rstd2 = rsqrtf(ss2 * (1.f / 512.f) - mean2 * mean2 + EPS_);
#pragma unroll
  for (int i = 0; i < 8; ++i) {
    int idx = i * 64 + lane;
    x0[(size_t)row * D_ + idx] = w[i];
    xln[(size_t)row * D_ + idx] = bf16r((w[i] - mean2) * rstd2 * g2[idx] + b2[idx]);
  }
}

// ---------------------------------------------------------------- final LN
__global__ __launch_bounds__(64) void ln_k(const float* __restrict__ x,
                                           const float* __restrict__ g,
                                           const float* __restrict__ bb,
                                           float* __restrict__ out) {
  int row = blockIdx.x, lane = threadIdx.x;
  const float* xr = x + (size_t)row * D_;
  float v[8];
  float s = 0.f, ss = 0.f;
#pragma unroll
  for (int i = 0; i < 8; ++i) {
    float t = xr[i * 64 + lane];
    v[i] = t; s += t; ss += t * t;
  }
  s = wsum(s); ss = wsum(ss);
  float mean = s * (1.f / 512.f);
  float rstd = rsqrtf(ss * (1.f / 512.f) - mean * mean + EPS_);
#pragma unroll
  for (int i = 0; i < 8; ++i) {
    int idx = i * 64 + lane;
    out[(size_t)row * D_ + idx] = (v[i] - mean) * rstd * g[idx] + bb[idx];
  }
}

// ---------------------------------------------------------------- GLU (bf16 in, f32 out)
__global__ __launch_bounds__(256) void glu_k(const ushort* __restrict__ t1,
                                             float* __restrict__ out) {
  int t = blockIdx.x * 256 + threadIdx.x;
  int c4 = t & 127;
  int r = t >> 7;
  const ushort* row = t1 + (size_t)r * (2 * D_);
  uint2 ua = *(const uint2*)&row[c4 * 4];
  uint2 ug = *(const uint2*)&row[D_ + c4 * 4];
  float4 o;
  o.x = bf2f(ua.x & 0xffffu) / (1.f + __expf(-bf2f(ug.x & 0xffffu)));
  o.y = bf2f(ua.x >> 16)     / (1.f + __expf(-bf2f(ug.x >> 16)));
  o.z = bf2f(ua.y & 0xffffu) / (1.f + __expf(-bf2f(ug.y & 0xffffu)));
  o.w = bf2f(ua.y >> 16)     / (1.f + __expf(-bf2f(ug.y >> 16)));
  *(float4*)&out[(size_t)r * D_ + c4 * 4] = o;
}

// ---------------------------------------------------------------- depthwise conv K=5 + bn + hardswish (f32 in, bf16 out)
__global__ __launch_bounds__(256) void convbn_k(
    const float* __restrict__ x, const float* __restrict__ w,
    const float* __restrict__ wb, const float* __restrict__ bng,
    const float* __restrict__ bnb, ushort* __restrict__ out) {
  int t = blockIdx.x * 256 + threadIdx.x;
  int c4 = t & 127;
  int l = (t >> 7) & 2047;
  int b = t >> 18;
  int d0 = c4 * 4;
  float accv[4] = {0.f, 0.f, 0.f, 0.f};
#pragma unroll
  for (int kt = 0; kt < 5; ++kt) {
    int ls = l + kt - 2;
    if (ls >= 0 && ls < L_) {
      float4 xv = *(const float4*)&x[((size_t)(b * L_ + ls)) * D_ + d0];
      const float* pv = &xv.x;
#pragma unroll
      for (int j = 0; j < 4; ++j) accv[j] += pv[j] * w[(d0 + j) * 5 + kt];
    }
  }
  const float bscale = rsqrtf(1.0f + EPS_);
  float po[4];
#pragma unroll
  for (int j = 0; j < 4; ++j) {
    int d = d0 + j;
    float vv = accv[j] + wb[d];
    vv = vv * (bng[d] * bscale) + bnb[d];
    float hs = fminf(fmaxf(vv + 3.f, 0.f), 6.f);
    po[j] = vv * hs * (1.f / 6.f);
  }
  uint lo = (uint)bf16r(po[0]) | ((uint)bf16r(po[1]) << 16);
  uint hi = (uint)bf16r(po[2]) | ((uint)bf16r(po[3]) << 16);
  uint2 o2 = {lo, hi};
  *(uint2*)&out[((size_t)(b * L_ + l)) * D_ + d0] = o2;
}

// ================================================================ launcher
extern "C" void kernel_launch(void* const* d_in, const int* in_sizes, int n_in,
                              void* d_out, int out_size, void* d_ws, size_t ws_size,
                              hipStream_t stream) {
  const float* src    = (const float*)d_in[0];
  const float* Wq     = (const float*)d_in[1];
  const float* bq     = (const float*)d_in[2];
  const float* Wk     = (const float*)d_in[3];
  const float* bk     = (const float*)d_in[4];
  const float* Wv     = (const float*)d_in[5];
  const float* bv     = (const float*)d_in[6];
  const float* Wo     = (const float*)d_in[7];
  const float* bo     = (const float*)d_in[8];
  const float* ln_g   = (const float*)d_in[9];
  const float* ln_b   = (const float*)d_in[10];
  const float* pw1_w  = (const float*)d_in[11];
  const float* pw1_b  = (const float*)d_in[12];
  const float* dw_w   = (const float*)d_in[13];
  const float* dw_b   = (const float*)d_in[14];
  const float* bn_g   = (const float*)d_in[15];
  const float* bn_b   = (const float*)d_in[16];
  const float* pw2_w  = (const float*)d_in[17];
  const float* pw2_b  = (const float*)d_in[18];
  const float* proj_w = (const float*)d_in[19];
  const float* proj_b = (const float*)d_in[20];
  const float* proj2_w= (const float*)d_in[21];
  const float* proj2_b= (const float*)d_in[22];
  const float* W1     = (const float*)d_in[23];
  const float* b1     = (const float*)d_in[24];
  const float* W2     = (const float*)d_in[25];
  const float* b2     = (const float*)d_in[26];
  const float* n1_g   = (const float*)d_in[27];
  const float* n1_b   = (const float*)d_in[28];
  const float* n2_g   = (const float*)d_in[29];
  const float* n2_b   = (const float*)d_in[30];
  float* out = (float*)d_out;

  char* wsb = (char*)d_ws;
  const size_t MB1 = 1 << 20;
  // weights (bf16), persistent
  ushort* wqkv = (ushort*)(wsb);                          // 1536x512
  ushort* wo_w = (ushort*)(wsb + 1536 * 1024);            // 512x512
  ushort* pw1w = (ushort*)(wsb + 2 * MB1);                // 1024x512
  ushort* pw2w = (ushort*)(wsb + 3 * MB1);                // 512x512
  ushort* pjww = (ushort*)(wsb + 3 * MB1 + 512 * 1024);   // 2048x2048
  ushort* pj2w = (ushort*)(wsb + 11 * MB1 + 1024 * 1024); // 512x512 @11.5M... 
  pj2w = (ushort*)(wsb + 11 * MB1 + 512 * 1024);
  ushort* w1w  = (ushort*)(wsb + 12 * MB1);               // 2048x512
  ushort* w2w  = (ushort*)(wsb + 14 * MB1);               // 512x2048
  float*  bqkv = (float*)(wsb + 16 * MB1);                // 1536 f32
  float*  tab  = (float*)(wsb + 16 * MB1 + 8192);         // L*32 f32
  // arena
  char* A0 = wsb + 17 * MB1;
  ushort* src_bf = (ushort*)A0;            // [1,2] 4MiB
  ushort* t1_bf  = (ushort*)A0;            // [8,9] 8MiB
  float*  x0     = (float*)(A0 + 8 * MB1); // [6,11] 8MiB
  ushort* ff_bf  = (ushort*)A0;            // [14,15] 16MiB
  char* B0 = A0 + 16 * MB1;
  ushort* Qb = (ushort*)B0;                // [2,4]
  ushort* Kb = (ushort*)(B0 + 4 * MB1);
  ushort* Vb = (ushort*)(B0 + 8 * MB1);
  float*  gluo    = (float*)B0;            // [9,10] 8MiB
  ushort* conv_bf = (ushort*)(B0 + 8 * MB1); // [10,11] 4MiB
  ushort* p_bf    = (ushort*)B0;           // [12,13] 4MiB
  float*  y       = (float*)(B0 + 4 * MB1); // [13,15] 8MiB
  char* C0 = B0 + 12 * MB1;
  ushort* ctx_bf = (ushort*)C0;            // [4,5] 4MiB
  ushort* x0T    = (ushort*)C0;            // [7,12] 4MiB
  ushort* y_bf   = (ushort*)C0;            // [13,14] 4MiB
  char* D0 = C0 + 4 * MB1;
  float* attnout = (float*)D0;             // [5,6] 8MiB
  float* bufC    = (float*)D0;             // [11,13] 8MiB
  float* zbuf    = (float*)D0;             // [15,16] 8MiB

  dim3 blk(256);

  // 1. convert weights + src to bf16
  CvtArgs ca;
  ca.s[0] = Wq;    ca.d[0] = wqkv;               ca.n[0] = 512 * 512;
  ca.s[1] = Wk;    ca.d[1] = wqkv + 512 * 512;   ca.n[1] = 512 * 512;
  ca.s[2] = Wv;    ca.d[2] = wqkv + 1024 * 512;  ca.n[2] = 512 * 512;
  ca.s[3] = Wo;    ca.d[3] = wo_w;               ca.n[3] = 512 * 512;
  ca.s[4] = pw1_w; ca.d[4] = pw1w;               ca.n[4] = 1024 * 512;
  ca.s[5] = pw2_w; ca.d[5] = pw2w;               ca.n[5] = 512 * 512;
  ca.s[6] = proj_w;ca.d[6] = pjww;               ca.n[6] = 2048 * 2048;
  ca.s[7] = proj2_w;ca.d[7] = pj2w;              ca.n[7] = 512 * 512;
  ca.s[8] = W1;    ca.d[8] = w1w;                ca.n[8] = 2048 * 512;
  ca.s[9] = W2;    ca.d[9] = w2w;                ca.n[9] = 512 * 2048;
  ca.s[10]= src;   ca.d[10]= src_bf;             ca.n[10]= BL_ * D_;
  cvt_all_k<<<dim3(2048, 11), blk, 0, stream>>>(ca);
  rope_table_k<<<(L_ * 16 + 255) / 256, blk, 0, stream>>>(tab);
  hipMemcpyAsync(bqkv, bq, 512 * 4, hipMemcpyDeviceToDevice, stream);
  hipMemcpyAsync(bqkv + 512, bk, 512 * 4, hipMemcpyDeviceToDevice, stream);
  hipMemcpyAsync(bqkv + 1024, bv, 512 * 4, hipMemcpyDeviceToDevice, stream);

  // 2. fused QKV + bias + RoPE -> Qb/Kb/Vb (bf16)
  gemm_bf_k<1,0,0,0,0,0><<<dim3(12, 32), blk, 0, stream>>>(
      src_bf, wqkv, bqkv, nullptr, nullptr, nullptr,
      BL_, 1536, 512, 0, 0, tab, Qb, Kb, Vb);

  // 4. attention
  attn_mfma_k<<<B_ * H_ * (L_ / 64), blk, 0, stream>>>(Qb, Kb, Vb, ctx_bf);

  // 5. Wo
  gemm_bf_k<0,0,0,0,1,0><<<dim3(4, 32), blk, 0, stream>>>(
      ctx_bf, wo_w, bo, nullptr, attnout, nullptr,
      BL_, 512, 512, 0, 0, nullptr, nullptr, nullptr, nullptr);

  // 6. x0 = src + LN(attnout); xln_bf = LN(x0)
  ln_res_ln_k<<<BL_, 64, 0, stream>>>(attnout, src, n1_g, n1_b, ln_g, ln_b,
                                      x0, src_bf /*reuse A0 as xln*/);
  // NOTE: xln shares A0 with t1_bf?  xln lives [6,8], t1_bf [8,9]: pw1 reads
  // xln while writing t1_bf -> MUST be disjoint. Put xln at A0+4MiB region?
  // x0 occupies A0+8..16. Use C0? x0T occupies C0 from step 7.
  // -> use D0+? attnout dead after this kernel. Safe choice: xln at
  //    (A0 + 4MiB) .. +4MiB (inside A0 slot, before x0 at +8MiB):
  //    t1_bf occupies A0..8MiB at step 8 -> CONFLICT with xln@A0+4.
  // Final: xln -> B0+8MiB (conv_bf slot, free until step 10). pw1(8) reads
  // xln, writes t1_bf@A0 ok; glu(9) reads t1 writes gluo@B0 (xln dead).

  // 7. transpose x0 -> x0T bf16
  transp_k<<<dim3(64, 16, 2), blk, 0, stream>>>(x0, x0T);

  // 8. pw1 -> t1_bf
  gemm_bf_k<0,0,0,0,0,1><<<dim3(8, 32), blk, 0, stream>>>(
      (const ushort*)(B0 + 8 * MB1) /*xln*/, pw1w, pw1_b, nullptr, nullptr, t1_bf,
      BL_, 1024, 512, 0, 0, nullptr, nullptr, nullptr, nullptr);

  // 9. GLU
  glu_k<<<(BL_ * (D_ / 4)) / 256, blk, 0, stream>>>(t1_bf, gluo);

  // 10. conv + bn + hswish -> conv_bf
  convbn_k<<<(B_ * L_ * (D_ / 4)) / 256, blk, 0, stream>>>(gluo, dw_w, dw_b,
                                                           bn_g, bn_b, conv_bf);

  // 11. pw2 + x0 -> bufC (f32)
  gemm_bf_k<0,0,0,1,1,0><<<dim3(4, 32), blk, 0, stream>>>(
      conv_bf, pw2w, pw2_b, x0, bufC, nullptr,
      BL_, 512, 512, 0, 0, nullptr, nullptr, nullptr, nullptr);

  // 12. proj: p[z] = proj_w @ x0[z]  (A=proj_w, W=x0T[z]), bias row
  gemm_bf_k<0,1,0,0,0,1><<<dim3(4, 16, 2), blk, 0, stream>>>(
      pjww, x0T, proj_b, nullptr, nullptr, p_bf,
      2048, 512, 2048, (long)512 * 2048, (long)2048 * 512,
      nullptr, nullptr, nullptr, nullptr);

  // 13. proj2 + bufC -> y (f32) + y_bf
  gemm_bf_k<0,0,0,1,1,1><<<dim3(4, 32), blk, 0, stream>>>(
      p_bf, pj2w, proj2_b, bufC, y, y_bf,
      BL_, 512, 512, 0, 0, nullptr, nullptr, nullptr, nullptr);

  // 14. W1 + gelu -> ff_bf
  gemm_bf_k<0,0,1,0,0,1><<<dim3(16, 32), blk, 0, stream>>>(
      y_bf, w1w, b1, nullptr, nullptr, ff_bf,
      BL_, 2048, 512, 0, 0, nullptr, nullptr, nullptr, nullptr);

  // 15. W2 + y -> zbuf (f32)
  gemm_bf_k<0,0,0,1,1,0><<<dim3(4, 32), blk, 0, stream>>>(
      ff_bf, w2w, b2, y, zbuf, nullptr,
      BL_, 512, 2048, 0, 0, nullptr, nullptr, nullptr, nullptr);

  // 16. final LN
  ln_k<<<BL_, 64, 0, stream>>>(zbuf, n2_g, n2_b, out);
}

// Round 4
// 296.031 us; speedup vs baseline: 5.6791x; 1.2251x over previous
//
#include <hip/hip_runtime.h>
#include <math.h>

#define B_ 2
#define L_ 2048
#define D_ 512
#define H_ 16
#define HD_ 32
#define FF_ 2048
#define BL_ 4096
#define EPS_ 1e-5f

typedef unsigned short ushort;
typedef unsigned int uint;
typedef __attribute__((ext_vector_type(8))) short bf16x8;
typedef __attribute__((ext_vector_type(4))) float f32x4;
typedef __attribute__((ext_vector_type(4))) uint u32x4;

__device__ __forceinline__ ushort bf16r(float f) {
  uint u = __float_as_uint(f);
  uint r = (u + 0x7FFFu + ((u >> 16) & 1u)) >> 16;
  return (ushort)r;
}
__device__ __forceinline__ float bf2f(uint u) { return __uint_as_float(u << 16); }

__device__ __forceinline__ float wsum(float v) {
#pragma unroll
  for (int o = 32; o; o >>= 1) v += __shfl_xor(v, o);
  return v;
}

__device__ __forceinline__ void gload16(const void* g, void* l) {
  __builtin_amdgcn_global_load_lds(
      (const __attribute__((address_space(1))) void*)g,
      (__attribute__((address_space(3))) void*)l, 16, 0, 0);
}

// ================================================================ bf16 MFMA GEMM
// C[m,n] = epi( sum_k A[m,k] * W[n,k] )
// TMv: 128 (4 waves 2x2, 64x64 each) or 64 (4 waves 1x4, 64x32 each)
// EPI=1: QKV+RoPE epilogue -> Qb/Kb/Vb bf16 (B,H,L,HD)  (TMv=128 only)
template <int TMv, int EPI, int BROW, int GELU, int RES, int OUTF, int OUTB>
__global__ __launch_bounds__(256, 2) void gemm_bf_k(
    const ushort* __restrict__ A, const ushort* __restrict__ W,
    const float* __restrict__ bias, const float* __restrict__ res,
    float* __restrict__ Cf, ushort* __restrict__ Cb,
    const int M, const int N, const int Kd, const long sW, const long sC,
    const float* __restrict__ tab, ushort* __restrict__ Qb,
    ushort* __restrict__ Kb, ushort* __restrict__ Vb) {
  __shared__ __align__(16) ushort As[TMv * 64];
  __shared__ __align__(16) ushort Ws[128 * 64];
  const int tid = threadIdx.x;
  const int wid = tid >> 6, lane = tid & 63;
  const int lane15 = lane & 15, lgrp = lane >> 4;
  constexpr int NF = (TMv == 128) ? 4 : 2;
  const int wm = (TMv == 128) ? (wid >> 1) : 0;
  const int wnoff = (TMv == 128) ? (wid & 1) * 64 : wid * 32;
  const int bm = blockIdx.y * TMv, bn = blockIdx.x * 128;
  const int z = blockIdx.z;
  const ushort* Wz = W + (size_t)z * sW;

  f32x4 acc[4][NF];
#pragma unroll
  for (int i = 0; i < 4; ++i)
#pragma unroll
    for (int j = 0; j < NF; ++j) acc[i][j] = (f32x4){0.f, 0.f, 0.f, 0.f};

  for (int k0 = 0; k0 < Kd; k0 += 64) {
    __syncthreads();
#pragma unroll
    for (int i = 0; i < TMv / 32; ++i) {
      const int cb = i * 256 + wid * 64;
      const int chunk = cb + lane;
      const int ml = chunk >> 3;
      const int c16 = (chunk & 7) ^ (ml & 7);
      gload16(A + (size_t)(bm + ml) * Kd + k0 + c16 * 8, &As[(size_t)cb * 8]);
    }
#pragma unroll
    for (int i = 0; i < 4; ++i) {
      const int cb = i * 256 + wid * 64;
      const int chunk = cb + lane;
      const int ml = chunk >> 3;
      const int c16 = (chunk & 7) ^ (ml & 7);
      gload16(Wz + (size_t)(bn + ml) * Kd + k0 + c16 * 8, &Ws[(size_t)cb * 8]);
    }
    __syncthreads();

    bf16x8 af[2][4], wf[2][NF];
#pragma unroll
    for (int kk = 0; kk < 2; ++kk) {
#pragma unroll
      for (int f = 0; f < 4; ++f) {
        const int ma = wm * 64 + f * 16 + lane15;
        const int ca = (kk * 4 + lgrp) ^ (ma & 7);
        af[kk][f] = *(const bf16x8*)&As[ma * 64 + ca * 8];
      }
#pragma unroll
      for (int f = 0; f < NF; ++f) {
        const int nb = wnoff + f * 16 + lane15;
        const int cw = (kk * 4 + lgrp) ^ (nb & 7);
        wf[kk][f] = *(const bf16x8*)&Ws[nb * 64 + cw * 8];
      }
    }
#pragma unroll
    for (int kk = 0; kk < 2; ++kk)
#pragma unroll
      for (int fm = 0; fm < 4; ++fm)
#pragma unroll
        for (int fn = 0; fn < NF; ++fn)
          acc[fm][fn] = __builtin_amdgcn_mfma_f32_16x16x32_bf16(
              af[kk][fm], wf[kk][fn], acc[fm][fn], 0, 0, 0);
  }

#pragma unroll
  for (int fm = 0; fm < 4; ++fm) {
#pragma unroll
    for (int fn = 0; fn < NF; ++fn) {
      const int n = bn + wnoff + fn * 16 + lane15;
      float bcol = 0.f;
      if (EPI == 1 || !BROW) bcol = bias[n];
#pragma unroll
      for (int r = 0; r < 4; ++r) {
        const int m = bm + wm * 64 + fm * 16 + lgrp * 4 + r;
        float val = acc[fm][fn][r];
        if (EPI == 1) {
          val += bcol;
          float p = __shfl_xor(val, 1);
          const int l = m & 2047, b = m >> 11;
          const int h = (n >> 5) & 15;
          if (n < 1024) {
            const int ch = n & 31, i2 = ch >> 1;
            const float cv = tab[l * 32 + i2], sv = tab[l * 32 + 16 + i2];
            const float o = (ch & 1) ? (p * sv + val * cv) : (val * cv - p * sv);
            const int dcol = (ch & 1) ? 16 + i2 : i2;
            if (n < 512)
              Qb[(((size_t)(b * 16 + h)) * 2048 + l) * 32 + dcol] =
                  bf16r(o * (0.1767766952966369f * 1.4426950408889634f));
            else
              Kb[(((size_t)(b * 16 + h)) * 2048 + l) * 32 + dcol] = bf16r(o);
          } else {
            Vb[(((size_t)(b * 16 + h)) * 2048 + l) * 32 + (n & 31)] = bf16r(val);
          }
        } else {
          val += BROW ? bias[m] : bcol;
          if (RES) val += res[(size_t)z * sC + (size_t)m * N + n];
          if (GELU) val = 0.5f * val * (1.f + erff(val * 0.70710678118654752f));
          const size_t o = (size_t)z * sC + (size_t)m * N + n;
          if (OUTF) Cf[o] = val;
          if (OUTB) Cb[o] = bf16r(val);
        }
      }
    }
  }
}

// ================================================================ weight/src -> bf16 conversion (11 segments)
struct CvtArgs {
  const float* s[11];
  ushort* d[11];
  int n[11];
};
__global__ __launch_bounds__(256) void cvt_all_k(CvtArgs a) {
  const int seg = blockIdx.y;
  const int n = a.n[seg];
  const int i = (blockIdx.x * 256 + threadIdx.x) * 8;
  if (i >= n) return;
  const float* s = a.s[seg] + i;
  float4 x = *(const float4*)s, y = *(const float4*)(s + 4);
  bf16x8 o;
  o[0] = (short)bf16r(x.x); o[1] = (short)bf16r(x.y);
  o[2] = (short)bf16r(x.z); o[3] = (short)bf16r(x.w);
  o[4] = (short)bf16r(y.x); o[5] = (short)bf16r(y.y);
  o[6] = (short)bf16r(y.z); o[7] = (short)bf16r(y.w);
  *(bf16x8*)(a.d[seg] + i) = o;
}

// ---------------------------------------------------------------- RoPE table
__global__ void rope_table_k(float* __restrict__ tab) {
  int t = blockIdx.x * 256 + threadIdx.x;
  if (t >= L_ * 16) return;
  int i = t & 15, l = t >> 4;
  float cv, sv;
  if (i < 8) {
    float inv0 = 1.0f / powf(10000.0f, (float)(2 * i) / 16.0f);
    float inv1 = 1.0f / powf(10000.0f, (float)(2 * i + 1) / 16.0f);
    cv = cosf((float)l * inv0);
    sv = cosf((float)l * inv1);
  } else {
    int ii = i - 8;
    float inv0 = 1.0f / powf(10000.0f, (float)(2 * ii) / 16.0f);
    float inv1 = 1.0f / powf(10000.0f, (float)(2 * ii + 1) / 16.0f);
    cv = sinf((float)l * inv0);
    sv = sinf((float)l * inv1);
  }
  tab[l * 32 + i] = cv;
  tab[l * 32 + 16 + i] = sv;
}

// ---------------------------------------------------------------- transpose x0 f32 -> x0T bf16 (B,D,L)
__global__ __launch_bounds__(256) void transp_k(const float* __restrict__ x,
                                                ushort* __restrict__ xT) {
  __shared__ float t[32][33];
  const int b = blockIdx.z, l0 = blockIdx.x * 32, d0 = blockIdx.y * 32;
  const int tx = threadIdx.x & 31, ty = threadIdx.x >> 5;
#pragma unroll
  for (int i = 0; i < 4; ++i)
    t[ty + i * 8][tx] = x[((size_t)(b * L_ + l0 + ty + i * 8)) * D_ + d0 + tx];
  __syncthreads();
#pragma unroll
  for (int i = 0; i < 4; ++i)
    xT[((size_t)(b * D_ + d0 + ty + i * 8)) * L_ + l0 + tx] =
        bf16r(t[tx][ty + i * 8]);
}

// ---------------------------------------------------------------- MFMA flash attention
// swapped QK^T (D[m=key][n=q]) -> P stays in registers for PV A-frag.
// static softmax shift m = slope*qg (exact): p = exp2(qk' - slope'*min(k,qg)).
// Q pre-scaled by scale*log2e in QKV epilogue; nslope = -slope*log2e here.
__global__ __launch_bounds__(256, 4) void attn_mfma_k(const ushort* __restrict__ q,
                                                      const ushort* __restrict__ k,
                                                      const ushort* __restrict__ v,
                                                      ushort* __restrict__ ctx) {
  __shared__ __align__(16) ushort K_lds[4][130][8];  // [dimslot][key][8]
  __shared__ __align__(16) uint V_lds[32][68];       // [dim][u32 keypair slot]
  const int tid = threadIdx.x;
  const int wid = tid >> 6, lane = tid & 63;
  const int s = lane >> 4, lr = lane & 15;
  const int bh = blockIdx.x >> 5;
  const int qb = (blockIdx.x & 31) * 64;
  const int h = bh & 15, bidx = bh >> 4;
  const float nslope = -exp2f(-0.5f * (float)h) * 1.4426950408889634f;
  const int qrow = qb + wid * 16 + lr;
  const float qgf = (float)qrow;
  bf16x8 qa = *(const bf16x8*)&q[((size_t)bh * L_ + qrow) * HD_ + s * 8];

  float lsum = 0.f;
  f32x4 acc0 = {0.f, 0.f, 0.f, 0.f}, acc1 = {0.f, 0.f, 0.f, 0.f};
  const ushort* kg = k + (size_t)bh * L_ * HD_;
  const ushort* vg = v + (size_t)bh * L_ * HD_;
  // key-pair (2m,2m+1) -> u32 slot: m=[t:2][hi:1][s:2][w1:1] -> t*16+s*4+hi*2+w1
  const int vslot = (lane & 48) + ((lane >> 1) & 3) * 4 + ((lane >> 3) & 1) * 2 + (lane & 1);

  for (int t0 = 0; t0 < L_; t0 += 128) {
    __syncthreads();
#pragma unroll
    for (int pass = 0; pass < 2; ++pass) {
      int id = tid + pass * 256;
      int key = id >> 2, slot = id & 3;
      *(bf16x8*)&K_lds[slot][key][0] =
          *(const bf16x8*)&kg[(size_t)(t0 + key) * HD_ + slot * 8];
    }
    {
      const ushort* g0 = vg + (size_t)(t0 + 2 * lane) * HD_ + wid * 8;
      u32x4 va = *(const u32x4*)g0;
      u32x4 vb = *(const u32x4*)(g0 + HD_);
#pragma unroll
      for (int w = 0; w < 4; ++w) {
        V_lds[wid * 8 + 2 * w][vslot] =
            __builtin_amdgcn_perm(vb[w], va[w], 0x05040100u);
        V_lds[wid * 8 + 2 * w + 1][vslot] =
            __builtin_amdgcn_perm(vb[w], va[w], 0x07060302u);
      }
    }
    __syncthreads();

    // QK^T swapped: sc[c] rows = keys c*16 + s*4 + r, col = q = lr
    f32x4 sc[8];
#pragma unroll
    for (int c = 0; c < 8; ++c) {
      bf16x8 kf = *(const bf16x8*)&K_lds[s][c * 16 + lr][0];
      f32x4 zz = {0.f, 0.f, 0.f, 0.f};
      sc[c] = __builtin_amdgcn_mfma_f32_16x16x32_bf16(kf, qa, zz, 0, 0, 0);
    }
    // p = exp2(qk' - slope'*min(kpos, qg))
    const float kb0 = (float)(t0 + s * 4);
#pragma unroll
    for (int c = 0; c < 8; ++c) {
      const float kc = kb0 + (float)(c * 16);
#pragma unroll
      for (int r = 0; r < 4; ++r) {
        float kpos = kc + (float)r;
        float mn = fminf(kpos, qgf);
        float p = exp2f(fmaf(nslope, mn, sc[c][r]));
        sc[c][r] = p;
        lsum += p;
      }
    }
    // PV: A-frag built in-register (truncating bf16 pack via v_perm)
#pragma unroll
    for (int t = 0; t < 4; ++t) {
      uint w0 = __builtin_amdgcn_perm(__float_as_uint(sc[2 * t][1]),
                                      __float_as_uint(sc[2 * t][0]), 0x07060302u);
      uint w1 = __builtin_amdgcn_perm(__float_as_uint(sc[2 * t][3]),
                                      __float_as_uint(sc[2 * t][2]), 0x07060302u);
      uint w2 = __builtin_amdgcn_perm(__float_as_uint(sc[2 * t + 1][1]),
                                      __float_as_uint(sc[2 * t + 1][0]), 0x07060302u);
      uint w3 = __builtin_amdgcn_perm(__float_as_uint(sc[2 * t + 1][3]),
                                      __float_as_uint(sc[2 * t + 1][2]), 0x07060302u);
      u32x4 pw = {w0, w1, w2, w3};
      bf16x8 pf = __builtin_bit_cast(bf16x8, pw);
      bf16x8 v0 = *(const bf16x8*)&V_lds[lr][t * 16 + s * 4];
      bf16x8 v1 = *(const bf16x8*)&V_lds[16 + lr][t * 16 + s * 4];
      acc0 = __builtin_amdgcn_mfma_f32_16x16x32_bf16(pf, v0, acc0, 0, 0, 0);
      acc1 = __builtin_amdgcn_mfma_f32_16x16x32_bf16(pf, v1, acc1, 0, 0, 0);
    }
  }
  // lsum: per-lane partial (q=lr fixed) -> reduce over 4 s-groups
  lsum += __shfl_xor(lsum, 16);
  lsum += __shfl_xor(lsum, 32);
#pragma unroll
  for (int r = 0; r < 4; ++r) {
    float ls = __shfl(lsum, s * 4 + r, 64);  // lsum for q-row s*4+r
    float il = 1.f / ls;
    int qg2 = qb + wid * 16 + s * 4 + r;
    ushort* op = ctx + ((size_t)(bidx * L_ + qg2)) * D_ + h * HD_;
    op[lr] = bf16r(acc0[r] * il);
    op[16 + lr] = bf16r(acc1[r] * il);
  }
}

// ---------------------------------------------------------------- x0 = res + LN(x), xln_bf = LN(x0)
__global__ __launch_bounds__(64) void ln_res_ln_k(
    const float* __restrict__ x, const float* __restrict__ res,
    const float* __restrict__ g1, const float* __restrict__ b1,
    const float* __restrict__ g2, const float* __restrict__ b2,
    float* __restrict__ x0, ushort* __restrict__ xln) {
  int row = blockIdx.x, lane = threadIdx.x;
  const float* xr = x + (size_t)row * D_;
  float v[8];
  float s = 0.f, ss = 0.f;
#pragma unroll
  for (int i = 0; i < 8; ++i) {
    float t = xr[i * 64 + lane];
    v[i] = t; s += t; ss += t * t;
  }
  s = wsum(s); ss = wsum(ss);
  float mean = s * (1.f / 512.f);
  float rstd = rsqrtf(ss * (1.f / 512.f) - mean * mean + EPS_);
  float w[8];
  float s2 = 0.f, ss2 = 0.f;
#pragma unroll
  for (int i = 0; i < 8; ++i) {
    int idx = i * 64 + lane;
    float t = res[(size_t)row * D_ + idx] + (v[i] - mean) * rstd * g1[idx] + b1[idx];
    w[i] = t; s2 += t; ss2 += t * t;
  }
  s2 = wsum(s2); ss2 = wsum(ss2);
  float mean2 = s2 * (1.f / 512.f);
  float rstd2 = rsqrtf(ss2 * (1.f / 512.f) - mean2 * mean2 + EPS_);
#pragma unroll
  for (int i = 0; i < 8; ++i) {
    int idx = i * 64 + lane;
    x0[(size_t)row * D_ + idx] = w[i];
    xln[(size_t)row * D_ + idx] = bf16r((w[i] - mean2) * rstd2 * g2[idx] + b2[idx]);
  }
}

// ---------------------------------------------------------------- final LN
__global__ __launch_bounds__(64) void ln_k(const float* __restrict__ x,
                                           const float* __restrict__ g,
                                           const float* __restrict__ bb,
                                           float* __restrict__ out) {
  int row = blockIdx.x, lane = threadIdx.x;
  const float* xr = x + (size_t)row * D_;
  float v[8];
  float s = 0.f, ss = 0.f;
#pragma unroll
  for (int i = 0; i < 8; ++i) {
    float t = xr[i * 64 + lane];
    v[i] = t; s += t; ss += t * t;
  }
  s = wsum(s); ss = wsum(ss);
  float mean = s * (1.f / 512.f);
  float rstd = rsqrtf(ss * (1.f / 512.f) - mean * mean + EPS_);
#pragma unroll
  for (int i = 0; i < 8; ++i) {
    int idx = i * 64 + lane;
    out[(size_t)row * D_ + idx] = (v[i] - mean) * rstd * g[idx] + bb[idx];
  }
}

// ---------------------------------------------------------------- GLU (bf16 in, f32 out)
__global__ __launch_bounds__(256) void glu_k(const ushort* __restrict__ t1,
                                             float* __restrict__ out) {
  int t = blockIdx.x * 256 + threadIdx.x;
  int c4 = t & 127;
  int r = t >> 7;
  const ushort* row = t1 + (size_t)r * (2 * D_);
  uint2 ua = *(const uint2*)&row[c4 * 4];
  uint2 ug = *(const uint2*)&row[D_ + c4 * 4];
  float4 o;
  o.x = bf2f(ua.x & 0xffffu) / (1.f + __expf(-bf2f(ug.x & 0xffffu)));
  o.y = bf2f(ua.x >> 16)     / (1.f + __expf(-bf2f(ug.x >> 16)));
  o.z = bf2f(ua.y & 0xffffu) / (1.f + __expf(-bf2f(ug.y & 0xffffu)));
  o.w = bf2f(ua.y >> 16)     / (1.f + __expf(-bf2f(ug.y >> 16)));
  *(float4*)&out[(size_t)r * D_ + c4 * 4] = o;
}

// ---------------------------------------------------------------- depthwise conv K=5 + bn + hardswish (f32 in, bf16 out)
__global__ __launch_bounds__(256) void convbn_k(
    const float* __restrict__ x, const float* __restrict__ w,
    const float* __restrict__ wb, const float* __restrict__ bng,
    const float* __restrict__ bnb, ushort* __restrict__ out) {
  int t = blockIdx.x * 256 + threadIdx.x;
  int c4 = t & 127;
  int l = (t >> 7) & 2047;
  int b = t >> 18;
  int d0 = c4 * 4;
  float accv[4] = {0.f, 0.f, 0.f, 0.f};
#pragma unroll
  for (int kt = 0; kt < 5; ++kt) {
    int ls = l + kt - 2;
    if (ls >= 0 && ls < L_) {
      float4 xv = *(const float4*)&x[((size_t)(b * L_ + ls)) * D_ + d0];
      const float* pv = &xv.x;
#pragma unroll
      for (int j = 0; j < 4; ++j) accv[j] += pv[j] * w[(d0 + j) * 5 + kt];
    }
  }
  const float bscale = rsqrtf(1.0f + EPS_);
  float po[4];
#pragma unroll
  for (int j = 0; j < 4; ++j) {
    int d = d0 + j;
    float vv = accv[j] + wb[d];
    vv = vv * (bng[d] * bscale) + bnb[d];
    float hs = fminf(fmaxf(vv + 3.f, 0.f), 6.f);
    po[j] = vv * hs * (1.f / 6.f);
  }
  uint lo = (uint)bf16r(po[0]) | ((uint)bf16r(po[1]) << 16);
  uint hi = (uint)bf16r(po[2]) | ((uint)bf16r(po[3]) << 16);
  uint2 o2 = {lo, hi};
  *(uint2*)&out[((size_t)(b * L_ + l)) * D_ + d0] = o2;
}

// ================================================================ launcher
extern "C" void kernel_launch(void* const* d_in, const int* in_sizes, int n_in,
                              void* d_out, int out_size, void* d_ws, size_t ws_size,
                              hipStream_t stream) {
  const float* src    = (const float*)d_in[0];
  const float* Wq     = (const float*)d_in[1];
  const float* bq     = (const float*)d_in[2];
  const float* Wk     = (const float*)d_in[3];
  const float* bk     = (const float*)d_in[4];
  const float* Wv     = (const float*)d_in[5];
  const float* bv     = (const float*)d_in[6];
  const float* Wo     = (const float*)d_in[7];
  const float* bo     = (const float*)d_in[8];
  const float* ln_g   = (const float*)d_in[9];
  const float* ln_b   = (const float*)d_in[10];
  const float* pw1_w  = (const float*)d_in[11];
  const float* pw1_b  = (const float*)d_in[12];
  const float* dw_w   = (const float*)d_in[13];
  const float* dw_b   = (const float*)d_in[14];
  const float* bn_g   = (const float*)d_in[15];
  const float* bn_b   = (const float*)d_in[16];
  const float* pw2_w  = (const float*)d_in[17];
  const float* pw2_b  = (const float*)d_in[18];
  const float* proj_w = (const float*)d_in[19];
  const float* proj_b = (const float*)d_in[20];
  const float* proj2_w= (const float*)d_in[21];
  const float* proj2_b= (const float*)d_in[22];
  const float* W1     = (const float*)d_in[23];
  const float* b1     = (const float*)d_in[24];
  const float* W2     = (const float*)d_in[25];
  const float* b2     = (const float*)d_in[26];
  const float* n1_g   = (const float*)d_in[27];
  const float* n1_b   = (const float*)d_in[28];
  const float* n2_g   = (const float*)d_in[29];
  const float* n2_b   = (const float*)d_in[30];
  float* out = (float*)d_out;

  char* wsb = (char*)d_ws;
  const size_t MB1 = 1 << 20;
  // weights (bf16)
  ushort* wqkv = (ushort*)(wsb);                          // 1536x512
  ushort* wo_w = (ushort*)(wsb + 1536 * 1024);            // 512x512
  ushort* pw1w = (ushort*)(wsb + 2 * MB1);                // 1024x512
  ushort* pw2w = (ushort*)(wsb + 3 * MB1);                // 512x512
  ushort* pjww = (ushort*)(wsb + 3 * MB1 + 512 * 1024);   // 2048x2048
  ushort* pj2w = (ushort*)(wsb + 11 * MB1 + 512 * 1024);  // 512x512
  ushort* w1w  = (ushort*)(wsb + 12 * MB1);               // 2048x512
  ushort* w2w  = (ushort*)(wsb + 14 * MB1);               // 512x2048
  float*  bqkv = (float*)(wsb + 16 * MB1);                // 1536 f32
  float*  tab  = (float*)(wsb + 16 * MB1 + 8192);         // L*32 f32
  // arena
  char* A0 = wsb + 17 * MB1;
  ushort* src_bf = (ushort*)A0;              // steps 1-2
  ushort* t1_bf  = (ushort*)A0;              // steps 8-9 (8MiB)
  float*  x0     = (float*)(A0 + 8 * MB1);   // steps 6-11 (8MiB)
  ushort* ff_bf  = (ushort*)A0;              // steps 14-15 (16MiB)
  char* B0 = A0 + 16 * MB1;
  ushort* Qb = (ushort*)B0;                  // steps 2-4
  ushort* Kb = (ushort*)(B0 + 4 * MB1);
  ushort* Vb = (ushort*)(B0 + 8 * MB1);
  ushort* xln_bf  = (ushort*)(B0 + 8 * MB1); // steps 6-8 (4MiB, after Vb dead)
  float*  gluo    = (float*)B0;              // steps 9-10 (8MiB)
  ushort* conv_bf = (ushort*)(B0 + 8 * MB1); // steps 10-11 (4MiB)
  ushort* p_bf    = (ushort*)B0;             // steps 12-13 (4MiB)
  float*  y       = (float*)(B0 + 4 * MB1);  // steps 13-15 (8MiB)
  char* C0 = B0 + 12 * MB1;
  ushort* ctx_bf = (ushort*)C0;              // steps 4-5
  ushort* x0T    = (ushort*)C0;              // steps 7-12
  ushort* y_bf   = (ushort*)C0;              // steps 13-14
  char* D0 = C0 + 4 * MB1;
  float* attnout = (float*)D0;               // steps 5-6
  float* bufC    = (float*)D0;               // steps 11-13
  float* zbuf    = (float*)D0;               // steps 15-16

  dim3 blk(256);

  // 1. convert weights + src to bf16
  CvtArgs ca;
  ca.s[0] = Wq;    ca.d[0] = wqkv;               ca.n[0] = 512 * 512;
  ca.s[1] = Wk;    ca.d[1] = wqkv + 512 * 512;   ca.n[1] = 512 * 512;
  ca.s[2] = Wv;    ca.d[2] = wqkv + 1024 * 512;  ca.n[2] = 512 * 512;
  ca.s[3] = Wo;    ca.d[3] = wo_w;               ca.n[3] = 512 * 512;
  ca.s[4] = pw1_w; ca.d[4] = pw1w;               ca.n[4] = 1024 * 512;
  ca.s[5] = pw2_w; ca.d[5] = pw2w;               ca.n[5] = 512 * 512;
  ca.s[6] = proj_w;ca.d[6] = pjww;               ca.n[6] = 2048 * 2048;
  ca.s[7] = proj2_w;ca.d[7] = pj2w;              ca.n[7] = 512 * 512;
  ca.s[8] = W1;    ca.d[8] = w1w;                ca.n[8] = 2048 * 512;
  ca.s[9] = W2;    ca.d[9] = w2w;                ca.n[9] = 512 * 2048;
  ca.s[10]= src;   ca.d[10]= src_bf;             ca.n[10]= BL_ * D_;
  cvt_all_k<<<dim3(2048, 11), blk, 0, stream>>>(ca);
  rope_table_k<<<(L_ * 16 + 255) / 256, blk, 0, stream>>>(tab);
  hipMemcpyAsync(bqkv, bq, 512 * 4, hipMemcpyDeviceToDevice, stream);
  hipMemcpyAsync(bqkv + 512, bk, 512 * 4, hipMemcpyDeviceToDevice, stream);
  hipMemcpyAsync(bqkv + 1024, bv, 512 * 4, hipMemcpyDeviceToDevice, stream);

  // 2. fused QKV + bias + RoPE -> Qb/Kb/Vb (Q pre-scaled by scale*log2e)
  gemm_bf_k<128,1,0,0,0,0,0><<<dim3(12, 32), blk, 0, stream>>>(
      src_bf, wqkv, bqkv, nullptr, nullptr, nullptr,
      BL_, 1536, 512, 0, 0, tab, Qb, Kb, Vb);

  // 4. attention
  attn_mfma_k<<<B_ * H_ * (L_ / 64), blk, 0, stream>>>(Qb, Kb, Vb, ctx_bf);

  // 5. Wo
  gemm_bf_k<64,0,0,0,0,1,0><<<dim3(4, 64), blk, 0, stream>>>(
      ctx_bf, wo_w, bo, nullptr, attnout, nullptr,
      BL_, 512, 512, 0, 0, nullptr, nullptr, nullptr, nullptr);

  // 6. x0 = src + LN(attnout); xln_bf = LN(x0)
  ln_res_ln_k<<<BL_, 64, 0, stream>>>(attnout, src, n1_g, n1_b, ln_g, ln_b,
                                      x0, xln_bf);

  // 7. transpose x0 -> x0T bf16
  transp_k<<<dim3(64, 16, 2), blk, 0, stream>>>(x0, x0T);

  // 8. pw1 -> t1_bf
  gemm_bf_k<128,0,0,0,0,0,1><<<dim3(8, 32), blk, 0, stream>>>(
      xln_bf, pw1w, pw1_b, nullptr, nullptr, t1_bf,
      BL_, 1024, 512, 0, 0, nullptr, nullptr, nullptr, nullptr);

  // 9. GLU
  glu_k<<<(BL_ * (D_ / 4)) / 256, blk, 0, stream>>>(t1_bf, gluo);

  // 10. conv + bn + hswish -> conv_bf
  convbn_k<<<(B_ * L_ * (D_ / 4)) / 256, blk, 0, stream>>>(gluo, dw_w, dw_b,
                                                           bn_g, bn_b, conv_bf);

  // 11. pw2 + x0 -> bufC (f32)
  gemm_bf_k<64,0,0,0,1,1,0><<<dim3(4, 64), blk, 0, stream>>>(
      conv_bf, pw2w, pw2_b, x0, bufC, nullptr,
      BL_, 512, 512, 0, 0, nullptr, nullptr, nullptr, nullptr);

  // 12. proj: p[z] = proj_w @ x0[z] + proj_b[row]
  gemm_bf_k<64,0,1,0,0,0,1><<<dim3(4, 32, 2), blk, 0, stream>>>(
      pjww, x0T, proj_b, nullptr, nullptr, p_bf,
      2048, 512, 2048, (long)512 * 2048, (long)2048 * 512,
      nullptr, nullptr, nullptr, nullptr);

  // 13. proj2 + bufC -> y (f32) + y_bf
  gemm_bf_k<64,0,0,0,1,1,1><<<dim3(4, 64), blk, 0, stream>>>(
      p_bf, pj2w, proj2_b, bufC, y, y_bf,
      BL_, 512, 512, 0, 0, nullptr, nullptr, nullptr, nullptr);

  // 14. W1 + gelu -> ff_bf
  gemm_bf_k<128,0,0,1,0,0,1><<<dim3(16, 32), blk, 0, stream>>>(
      y_bf, w1w, b1, nullptr, nullptr, ff_bf,
      BL_, 2048, 512, 0, 0, nullptr, nullptr, nullptr, nullptr);

  // 15. W2 + y -> zbuf (f32)
  gemm_bf_k<64,0,0,0,1,1,0><<<dim3(4, 64), blk, 0, stream>>>(
      ff_bf, w2w, b2, y, zbuf, nullptr,
      BL_, 512, 2048, 0, 0, nullptr, nullptr, nullptr, nullptr);

  // 16. final LN
  ln_k<<<BL_, 64, 0, stream>>>(zbuf, n2_g, n2_b, out);
}